// Round 8
// baseline (1371.350 us; speedup 1.0000x reference)
//
#include <hip/hip_runtime.h>
#include <math.h>

typedef __bf16 bf16x8 __attribute__((ext_vector_type(8)));
typedef float f32x4 __attribute__((ext_vector_type(4)));
typedef short short8 __attribute__((ext_vector_type(8)));
typedef unsigned int uint4v __attribute__((ext_vector_type(4)));

__device__ __forceinline__ float bf2f(unsigned short u) {
  union { unsigned int i; float f; } v; v.i = ((unsigned int)u) << 16; return v.f;
}
__device__ __forceinline__ unsigned short f2bf(float f) {
  union { float fl; unsigned int i; } v; v.fl = f;
  unsigned int x = v.i;
  return (unsigned short)((x + 0x7FFFu + ((x >> 16) & 1u)) >> 16);  // RNE
}
__device__ __forceinline__ unsigned int cvt_pk_bf16(float lo, float hi) {
  unsigned int r;
  asm("v_cvt_pk_bf16_f32 %0, %1, %2" : "=v"(r) : "v"(lo), "v"(hi));
  return r;
}
// async global->LDS, 16B per lane. lds ptr wave-uniform (HW adds lane*16).
__device__ __forceinline__ void gl_lds16(const unsigned short* g, void* l) {
  __builtin_amdgcn_global_load_lds(
      (const __attribute__((address_space(1))) unsigned int*)g,
      (__attribute__((address_space(3))) unsigned int*)l, 16, 0, 0);
}

// ============================================================================
// 256x256 bf16 GEMM, 16x16x32 MFMA, 4-phase K-tile schedule, 0 K-loop bank
// conflicts. R8: A TRIPLE-buffered (96KB) + B double-buffered (64KB) = 160KB
// LDS; both operands now staged ~7 phases before their deadline, steady-state
// tile-end wait vmcnt(8) (2 full tiles in flight).
//  BATCH=0: 1D grid, XCD-chunked + 4x4 super-tiled mapping. BATCH=1: batched.
//  SPLIT3: N spans 3 concatenated 4096-col groups (bias/output per tn>>12).
// ============================================================================
template<int BATCH, int SPLIT3, int CF32, int HAS_BIAS>
__global__ __launch_bounds__(512)
void gemm256(const unsigned short* __restrict__ A,
             const unsigned short* __restrict__ B,
             const float* __restrict__ b0, const float* __restrict__ b1,
             const float* __restrict__ b2,
             void* __restrict__ C0, void* __restrict__ C1, void* __restrict__ C2,
             int K, int lda, int ldb, int ldc, int nbn, float alpha,
             long sAo, long sAi, int nAi,
             long sBo, long sBi, int nBi,
             long sCo, long sCi, int nCi)
{
  // A slots: 3 x 32KB at 0/32768/65536 (slot = t % 3)
  // B slots: 2 x 32KB at 98304 + (t&1)*32768
  __shared__ alignas(16) unsigned char LDS[163840];
  const int NT = K >> 6;   // even, >= 2

  int tm, tn;
  long offA = 0, offB = 0, offC = 0;
  if (BATCH) {
    const int bx = (int)blockIdx.x;
    tm = (bx / nbn) * 256;
    tn = (bx % nbn) * 256;
    const int z = (int)blockIdx.z;
    offA = (long)(z / nAi) * sAo + (long)(z % nAi) * sAi;
    offB = (long)(z / nBi) * sBo + (long)(z % nBi) * sBi;
    offC = (long)(z / nCi) * sCo + (long)(z % nCi) * sCi;
  } else {
    const int nwg = (int)gridDim.x;
    const int bid = (int)blockIdx.x;
    const int s = (bid & 7) * (nwg >> 3) + (bid >> 3);
    const int sTile = s >> 4, w = s & 15;
    const int snb = nbn >> 2;
    tm = ((sTile / snb) * 4 + (w >> 2)) * 256;
    tn = ((sTile % snb) * 4 + (w & 3)) * 256;
  }

  const int tid = (int)threadIdx.x;
  const int lane = tid & 63;
  const int wv = tid >> 6;      // 0..7
  const int wm = wv >> 2;       // 0..1 (A half)
  const int wn = wv & 3;        // 0..3
  const int l16 = lane & 15;
  const int kg = lane >> 4;

  // staging: linear LDS dest; content[o] = logical[o ^ ((row&7)<<4)], row=o>>7
  const int srow = tid >> 3;
  const int scolb = ((tid & 7) * 16) ^ (((tid >> 3) & 7) << 4);
  const unsigned short* Abase = A + offA + (long)tm * lda + (scolb >> 1);
  const unsigned short* Bbase = B + offB + (long)tn * ldb + (scolb >> 1);
  const int ldsw = wv * 1024;

  // frag read cols (full-XOR swizzle on byte col, row&7 == l16&7)
  const int colswz0 = (kg * 16) ^ ((l16 & 7) << 4);
  const int colswz1 = (64 + kg * 16) ^ ((l16 & 7) << 4);

  f32x4 acc[8][4];
  #pragma unroll
  for (int i = 0; i < 8; ++i)
    #pragma unroll
    for (int j = 0; j < 4; ++j)
      #pragma unroll
      for (int e = 0; e < 4; ++e) acc[i][j][e] = 0.f;

  auto stageAh = [&](int t, int slot, int h) {   // one A half-tile (2 loads)
    #pragma unroll
    for (int i = 0; i < 2; ++i)
      gl_lds16(Abase + (long)(h * 128 + srow + i * 64) * lda + t * 64,
               &LDS[slot * 32768 + h * 16384 + i * 8192 + ldsw]);
  };
  auto stageBh = [&](int t, int h) {             // one B half-tile (2 loads)
    const int buf = t & 1;
    #pragma unroll
    for (int i = 0; i < 2; ++i)
      gl_lds16(Bbase + (long)(h * 128 + srow + i * 64) * ldb + t * 64,
               &LDS[98304 + buf * 32768 + h * 16384 + i * 8192 + ldsw]);
  };

  // prologue FIFO: A0(4) B0(4) A1(4) B1(4); vmcnt(8) drains A0,B0
  stageAh(0, 0, 0); stageAh(0, 0, 1);
  stageBh(0, 0);    stageBh(0, 1);
  stageAh(1, 1, 0); stageAh(1, 1, 1);
  stageBh(1, 0);    stageBh(1, 1);
  asm volatile("s_waitcnt vmcnt(8)" ::: "memory");
  __builtin_amdgcn_s_barrier();

  // Ledger (steady state), per tile t:
  //  j0: read 4A+8B frags; issue A(t+2)h0 -> slot (t+2)%3; lgkmcnt(8) hoist
  //  j1: read 4A; issue A(t+2)h1
  //  j2: read 4A; issue B(t+2)h0 -> B(t)'s slot (B(t) drained at j0 by all
  //      waves before the j0-end barrier)
  //  j3: read 4A; issue B(t+2)h1; tile-end FIFO = [A(t+1)4 B(t+1)4 | A(t+2)4
  //      B(t+2)4] -> vmcnt(8) drains exactly tile t+1, keeps t+2 in flight.
  //  A slot safety: slot (t+2)%3 holds A(t-1); its readers drained at the
  //  end-of-tile(t-1) barrier, which precedes tile t's j0 staging.
  for (int t = 0; t < NT; ++t) {
    const unsigned char* aB = &LDS[(t % 3) * 32768 + wm * 16384];
    const unsigned char* bB = &LDS[98304 + (t & 1) * 32768 + (wn >> 1) * 16384];
    const int sA = (t + 2) % 3;
    const int brow = (wn & 1) * 64;
    bf16x8 bfrag[4][2];
    #pragma unroll
    for (int j = 0; j < 4; ++j) {
      // ds-load this quadrant's A rows
      bf16x8 a0k0 = *(const bf16x8*)(aB + ((2 * j + 0) * 16 + l16) * 128 + colswz0);
      bf16x8 a0k1 = *(const bf16x8*)(aB + ((2 * j + 0) * 16 + l16) * 128 + colswz1);
      bf16x8 a1k0 = *(const bf16x8*)(aB + ((2 * j + 1) * 16 + l16) * 128 + colswz0);
      bf16x8 a1k1 = *(const bf16x8*)(aB + ((2 * j + 1) * 16 + l16) * 128 + colswz1);
      if (j == 0) {
        #pragma unroll
        for (int ni = 0; ni < 4; ++ni) {
          bfrag[ni][0] = *(const bf16x8*)(bB + (brow + ni * 16 + l16) * 128 + colswz0);
          bfrag[ni][1] = *(const bf16x8*)(bB + (brow + ni * 16 + l16) * 128 + colswz1);
        }
        if (t + 2 < NT) stageAh(t + 2, sA, 0);
        asm volatile("s_waitcnt lgkmcnt(8)" ::: "memory");   // drain 4 oldest (A rows)
      } else if (j == 1) {
        if (t + 2 < NT) stageAh(t + 2, sA, 1);
      } else if (j == 2) {
        if (t + 2 < NT) stageBh(t + 2, 0);
      } else {
        if (t + 2 < NT) stageBh(t + 2, 1);
      }
      __builtin_amdgcn_s_barrier();
      asm volatile("s_waitcnt lgkmcnt(0)" ::: "memory");
      __builtin_amdgcn_sched_barrier(0);
      __builtin_amdgcn_s_setprio(1);
      #pragma unroll
      for (int ni = 0; ni < 4; ++ni) {
        acc[2 * j + 0][ni] = __builtin_amdgcn_mfma_f32_16x16x32_bf16(a0k0, bfrag[ni][0], acc[2 * j + 0][ni], 0, 0, 0);
        acc[2 * j + 0][ni] = __builtin_amdgcn_mfma_f32_16x16x32_bf16(a0k1, bfrag[ni][1], acc[2 * j + 0][ni], 0, 0, 0);
        acc[2 * j + 1][ni] = __builtin_amdgcn_mfma_f32_16x16x32_bf16(a1k0, bfrag[ni][0], acc[2 * j + 1][ni], 0, 0, 0);
        acc[2 * j + 1][ni] = __builtin_amdgcn_mfma_f32_16x16x32_bf16(a1k1, bfrag[ni][1], acc[2 * j + 1][ni], 0, 0, 0);
      }
      __builtin_amdgcn_s_setprio(0);
      if (j == 3) {
        // t < NT-2: drain tile t+1 (8 oldest), keep tile t+2 in flight
        if (t >= NT - 2) { asm volatile("s_waitcnt vmcnt(0)" ::: "memory"); }
        else             { asm volatile("s_waitcnt vmcnt(8)" ::: "memory"); }
        __builtin_amdgcn_sched_barrier(0);
      }
      __builtin_amdgcn_s_barrier();
    }
  }
  // last tile-end barrier passed: all waves' ds_reads drained -> LDS reusable

  // epilogue
  const int which = SPLIT3 ? (tn >> 12) : 0;
  const float* bp = SPLIT3 ? (which == 0 ? b0 : (which == 1 ? b1 : b2)) : b0;
  void* Cp = SPLIT3 ? (which == 0 ? C0 : (which == 1 ? C1 : C2)) : C0;
  const int tnn = SPLIT3 ? (tn & 4095) : tn;

  if (CF32) {
    // f32 path (final GEMM only): direct stores
    #pragma unroll
    for (int ni = 0; ni < 4; ++ni) {
      const int col = tnn + wn * 64 + ni * 16 + l16;
      const float bv = HAS_BIAS ? bp[col] : 0.f;
      #pragma unroll
      for (int mi = 0; mi < 8; ++mi)
        #pragma unroll
        for (int jj = 0; jj < 4; ++jj) {
          const int row = tm + wm * 128 + mi * 16 + kg * 4 + jj;
          ((float*)Cp)[offC + (long)row * ldc + col] = acc[mi][ni][jj] * alpha + bv;
        }
    }
  } else {
    // bf16 path: per-wave LDS transpose -> fully coalesced 128B row segments
    unsigned short* lw = (unsigned short*)&LDS[wv * 16384];  // private 16KB
    #pragma unroll
    for (int ni = 0; ni < 4; ++ni) {
      const float bv = HAS_BIAS ? bp[tnn + wn * 64 + ni * 16 + l16] : 0.f;
      #pragma unroll
      for (int mi = 0; mi < 8; ++mi)
        #pragma unroll
        for (int jj = 0; jj < 4; ++jj)
          lw[(mi * 16 + kg * 4 + jj) * 64 + ni * 16 + l16] =
              f2bf(acc[mi][ni][jj] * alpha + bv);
    }
    asm volatile("s_waitcnt lgkmcnt(0)" ::: "memory");
    __builtin_amdgcn_sched_barrier(0);
    unsigned short* Cg = (unsigned short*)Cp + offC +
                         (long)(tm + wm * 128) * ldc + tnn + wn * 64;
    const int rr = lane >> 3, cc = (lane & 7) * 8;
    #pragma unroll
    for (int i = 0; i < 16; ++i) {
      short8 val = *(const short8*)&lw[(i * 8 + rr) * 64 + cc];
      *(short8*)(Cg + (long)(i * 8 + rr) * ldc + cc) = val;
    }
  }
}

// ============================================================================
// f32 -> bf16 convert (vectorized, grid-stride), n8 = n/8
// ============================================================================
__global__ __launch_bounds__(256)
void cvt_bf16(const float* __restrict__ in, unsigned short* __restrict__ out, long n8)
{
  long i = (long)blockIdx.x * 256 + threadIdx.x;
  const long stride = (long)gridDim.x * 256;
  for (; i < n8; i += stride) {
    f32x4 v0 = *(const f32x4*)(in + i * 8);
    f32x4 v1 = *(const f32x4*)(in + i * 8 + 4);
    uint4v o;
    o[0] = cvt_pk_bf16(v0[0], v0[1]);
    o[1] = cvt_pk_bf16(v0[2], v0[3]);
    o[2] = cvt_pk_bf16(v1[0], v1[1]);
    o[3] = cvt_pk_bf16(v1[2], v1[3]);
    *(uint4v*)(out + i * 8) = o;
  }
}

// In-place LayerNorm over rows of 512 bf16. One wave/row. g,b f32.
__global__ __launch_bounds__(256)
void ln_rows(unsigned short* __restrict__ t, const float* __restrict__ g,
             const float* __restrict__ b)
{
  const int row = blockIdx.x * 4 + ((int)threadIdx.x >> 6);
  const int lane = (int)threadIdx.x & 63;
  unsigned short* p = t + (long)row * 512 + lane * 8;
  short8 rv = *(const short8*)p;
  float x[8];
  #pragma unroll
  for (int j = 0; j < 8; ++j) x[j] = bf2f((unsigned short)rv[j]);
  float s = 0.f;
  #pragma unroll
  for (int j = 0; j < 8; ++j) s += x[j];
  #pragma unroll
  for (int off = 32; off > 0; off >>= 1) s += __shfl_xor(s, off, 64);
  float mu = s * (1.f / 512.f);
  float vs = 0.f;
  #pragma unroll
  for (int j = 0; j < 8; ++j) { float d = x[j] - mu; vs += d * d; }
  #pragma unroll
  for (int off = 32; off > 0; off >>= 1) vs += __shfl_xor(vs, off, 64);
  float rs = rsqrtf(vs * (1.f / 512.f) + 1e-5f);
  f32x4 gv0 = *(const f32x4*)(g + lane * 8);
  f32x4 gv1 = *(const f32x4*)(g + lane * 8 + 4);
  f32x4 bv0 = *(const f32x4*)(b + lane * 8);
  f32x4 bv1 = *(const f32x4*)(b + lane * 8 + 4);
  short8 ov;
  #pragma unroll
  for (int j = 0; j < 4; ++j) ov[j] = (short)f2bf((x[j] - mu) * rs * gv0[j] + bv0[j]);
  #pragma unroll
  for (int j = 0; j < 4; ++j) ov[4 + j] = (short)f2bf((x[4 + j] - mu) * rs * gv1[j] + bv1[j]);
  *(short8*)p = ov;
}

// w = (val * gelu_exact(gate)) / max(||.||2, 1e-12); h rows are 1024 (val|gate)
__global__ __launch_bounds__(256)
void gate_norm(const unsigned short* __restrict__ h, unsigned short* __restrict__ w)
{
  const int row = blockIdx.x * 4 + ((int)threadIdx.x >> 6);
  const int lane = (int)threadIdx.x & 63;
  const unsigned short* hp = h + (long)row * 1024 + lane * 8;
  short8 vv = *(const short8*)hp;
  short8 gg = *(const short8*)(hp + 512);
  float wv[8];
  float ssq = 0.f;
  #pragma unroll
  for (int j = 0; j < 8; ++j) {
    float val = bf2f((unsigned short)vv[j]);
    float gt  = bf2f((unsigned short)gg[j]);
    float tt  = val * (0.5f * gt * (1.f + erff(gt * 0.70710678118654752f)));
    wv[j] = tt;
    ssq += tt * tt;
  }
  #pragma unroll
  for (int off = 32; off > 0; off >>= 1) ssq += __shfl_xor(ssq, off, 64);
  float scale = 1.f / fmaxf(sqrtf(ssq), 1e-12f);
  short8 ov;
  #pragma unroll
  for (int j = 0; j < 8; ++j) ov[j] = (short)f2bf(wv[j] * scale);
  *(short8*)(w + (long)row * 512 + lane * 8) = ov;
}

// v (B,S,E) bf16 -> vT (B*H, 512d, 512t)
__global__ __launch_bounds__(256)
void transpose_v(const unsigned short* __restrict__ v, unsigned short* __restrict__ vT)
{
  __shared__ alignas(16) unsigned short lt[64][72];
  const int bh = blockIdx.z;
  const int b = bh >> 3, hh = bh & 7;
  const int d0 = blockIdx.x * 64, t0 = blockIdx.y * 64;
  const int tid = (int)threadIdx.x;
  const unsigned short* src = v + (long)b * (512L * 4096L) + hh * 512;
  #pragma unroll
  for (int it = 0; it < 2; ++it) {
    int ci = it * 256 + tid;
    int r = ci >> 3, c8 = (ci & 7) * 8;
    *(short8*)&lt[r][c8] = *(const short8*)(src + (long)(t0 + r) * 4096 + d0 + c8);
  }
  __syncthreads();
  unsigned short* dst = vT + ((long)bh * 512 + d0) * 512 + t0;
  #pragma unroll
  for (int it = 0; it < 2; ++it) {
    int ci = it * 256 + tid;
    int rr = ci >> 3, c8 = (ci & 7) * 8;
    short8 o;
    #pragma unroll
    for (int j = 0; j < 8; ++j) o[j] = (short)lt[c8 + j][rr];
    *(short8*)(dst + (long)rr * 512 + c8) = o;
  }
}

extern "C" void kernel_launch(void* const* d_in, const int* in_sizes, int n_in,
                              void* d_out, int out_size, void* d_ws, size_t ws_size,
                              hipStream_t stream)
{
  (void)in_sizes; (void)n_in; (void)out_size; (void)ws_size;
  const float* x   = (const float*)d_in[0];
  const float* Wq  = (const float*)d_in[1];
  const float* bq  = (const float*)d_in[2];
  const float* Wk  = (const float*)d_in[3];
  const float* bk  = (const float*)d_in[4];
  const float* Wv  = (const float*)d_in[5];
  const float* bv  = (const float*)d_in[6];
  const float* g_q = (const float*)d_in[7];
  const float* b_q = (const float*)d_in[8];
  const float* g_k = (const float*)d_in[9];
  const float* b_k = (const float*)d_in[10];
  const float* Wg  = (const float*)d_in[11];
  const float* bg  = (const float*)d_in[12];
  const float* Wo  = (const float*)d_in[13];
  const float* bo  = (const float*)d_in[14];
  float* out = (float*)d_out;

  const long NE  = 33554432L;   // B*S*E
  const long NE2 = NE / 2;      // 4096*4096
  unsigned short* ws    = (unsigned short*)d_ws;
  unsigned short* xb    = ws;                    // NE
  unsigned short* Wqkv  = ws + NE;               // 1.5*NE (Wq|Wk|Wv rows)
  unsigned short* qbuf  = ws + NE + 3 * NE2;     // NE
  unsigned short* kbuf  = qbuf + NE;             // NE
  unsigned short* vbuf  = kbuf + NE;             // NE
  unsigned short* Wgb   = Wqkv;                  // 1024x512 (after proj)
  unsigned short* Wob   = Wqkv + 524288;         // 4096x4096 (after proj)
  unsigned short* sbuf  = xb;                    // scores (x dead)
  unsigned short* vT    = qbuf;                  // q dead after scores
  unsigned short* hbuf  = kbuf;                  // spans kbuf+vbuf, both dead
  unsigned short* wbuf  = xb;                    // scores dead after h-GEMM
  unsigned short* obuf  = kbuf;                  // h dead after gate_norm

  dim3 blk256(256), blk512(512);
  const float isq = 0.044194173824159216f;  // 1/sqrt(512)

  cvt_bf16<<<16384, blk256, 0, stream>>>(x, xb, NE / 8);
  cvt_bf16<<<8192, blk256, 0, stream>>>(Wq, Wqkv, NE2 / 8);
  cvt_bf16<<<8192, blk256, 0, stream>>>(Wk, Wqkv + NE2, NE2 / 8);
  cvt_bf16<<<8192, blk256, 0, stream>>>(Wv, Wqkv + 2 * NE2, NE2 / 8);

  // merged q|k|v projection: (8192 x 12288) = xb @ Wqkv^T, split-3 epilogue
  gemm256<0, 1, 0, 1><<<1536, blk512, 0, stream>>>(
      xb, Wqkv, bq, bk, bv, qbuf, kbuf, vbuf,
      4096, 4096, 4096, 4096, 48, 1.f,
      0L, 0L, 1, 0L, 0L, 1, 0L, 0L, 1);

  // Wqkv dead -> convert Wg, Wo into its region
  cvt_bf16<<<256, blk256, 0, stream>>>(Wg, Wgb, 524288L / 8);
  cvt_bf16<<<8192, blk256, 0, stream>>>(Wo, Wob, NE2 / 8);

  ln_rows<<<16384, blk256, 0, stream>>>(qbuf, g_q, b_q);
  ln_rows<<<16384, blk256, 0, stream>>>(kbuf, g_k, b_k);

  // scores = q @ k^T / sqrt(HD), per (b,h) -> sbuf (=xb)
  gemm256<1, 0, 0, 0><<<dim3(4, 1, 128), blk512, 0, stream>>>(
      qbuf, kbuf, nullptr, nullptr, nullptr, sbuf, nullptr, nullptr,
      512, 4096, 4096, 512, 2, isq,
      2097152L, 512L, 8,
      2097152L, 512L, 8,
      262144L, 0L, 1);

  transpose_v<<<dim3(8, 8, 128), blk256, 0, stream>>>(vbuf, vT);

  // h = scores @ Wg^T + bg -> hbuf (=kbuf..vbuf)
  gemm256<1, 0, 0, 1><<<dim3(8, 1, 128), blk512, 0, stream>>>(
      sbuf, Wgb, bg, nullptr, nullptr, hbuf, nullptr, nullptr,
      512, 512, 512, 1024, 4, 1.f,
      262144L, 0L, 1,
      0L, 0L, 1,
      524288L, 0L, 1);

  gate_norm<<<16384, blk256, 0, stream>>>(hbuf, wbuf);

  // attn_out = w @ vT^T -> obuf, (B,S,E) layout
  gemm256<1, 0, 0, 0><<<dim3(4, 1, 128), blk512, 0, stream>>>(
      wbuf, vT, nullptr, nullptr, nullptr, obuf, nullptr, nullptr,
      512, 512, 512, 4096, 2, 1.f,
      262144L, 0L, 1,
      262144L, 0L, 1,
      2097152L, 512L, 8);

  // final = attn_out @ Wo^T + bo -> d_out (f32)
  gemm256<0, 0, 1, 1><<<512, blk512, 0, stream>>>(
      obuf, Wob, bo, nullptr, nullptr, out, nullptr, nullptr,
      4096, 4096, 4096, 4096, 16, 1.f,
      0L, 0L, 1, 0L, 0L, 1, 0L, 0L, 1);
}

// Round 9
// 1295.662 us; speedup vs baseline: 1.0584x; 1.0584x over previous
//
#include <hip/hip_runtime.h>
#include <math.h>

typedef __bf16 bf16x8 __attribute__((ext_vector_type(8)));
typedef float f32x4 __attribute__((ext_vector_type(4)));
typedef short short8 __attribute__((ext_vector_type(8)));
typedef unsigned int uint4v __attribute__((ext_vector_type(4)));

__device__ __forceinline__ float bf2f(unsigned short u) {
  union { unsigned int i; float f; } v; v.i = ((unsigned int)u) << 16; return v.f;
}
__device__ __forceinline__ unsigned short f2bf(float f) {
  union { float fl; unsigned int i; } v; v.fl = f;
  unsigned int x = v.i;
  return (unsigned short)((x + 0x7FFFu + ((x >> 16) & 1u)) >> 16);  // RNE
}
__device__ __forceinline__ unsigned int cvt_pk_bf16(float lo, float hi) {
  unsigned int r;
  asm("v_cvt_pk_bf16_f32 %0, %1, %2" : "=v"(r) : "v"(lo), "v"(hi));
  return r;
}
// async global->LDS, 16B per lane. lds ptr wave-uniform (HW adds lane*16).
__device__ __forceinline__ void gl_lds16(const unsigned short* g, void* l) {
  __builtin_amdgcn_global_load_lds(
      (const __attribute__((address_space(1))) unsigned int*)g,
      (__attribute__((address_space(3))) unsigned int*)l, 16, 0, 0);
}

// ============================================================================
// 256x256 bf16 GEMM, 16x16x32 MFMA. R9: MINIMAL-BARRIER schedule — only the
// 2 hazard-required barriers per K-tile (j1-end: B-slot reuse; tile-end:
// DMA visibility). Waves drift within the tile -> cross-wave MFMA/ds_read
// overlap without a second block. A/B double-buffered, 128KB LDS, counted
// vmcnt, 0 K-loop bank conflicts, LDS-transpose bf16 epilogue.
//  BATCH=0: 1D grid, XCD-chunked + 4x4 super-tiled mapping. BATCH=1: batched.
//  SPLIT3: N spans 3 concatenated 4096-col groups (bias/output per tn>>12).
// ============================================================================
template<int BATCH, int SPLIT3, int CF32, int HAS_BIAS>
__global__ __launch_bounds__(512)
void gemm256(const unsigned short* __restrict__ A,
             const unsigned short* __restrict__ B,
             const float* __restrict__ b0, const float* __restrict__ b1,
             const float* __restrict__ b2,
             void* __restrict__ C0, void* __restrict__ C1, void* __restrict__ C2,
             int K, int lda, int ldb, int ldc, int nbn, float alpha,
             long sAo, long sAi, int nAi,
             long sBo, long sBi, int nBi,
             long sCo, long sCi, int nCi)
{
  __shared__ alignas(16) unsigned char LDS[131072];
  const int NT = K >> 6;   // even, >= 2

  int tm, tn;
  long offA = 0, offB = 0, offC = 0;
  if (BATCH) {
    const int bx = (int)blockIdx.x;
    tm = (bx / nbn) * 256;
    tn = (bx % nbn) * 256;
    const int z = (int)blockIdx.z;
    offA = (long)(z / nAi) * sAo + (long)(z % nAi) * sAi;
    offB = (long)(z / nBi) * sBo + (long)(z % nBi) * sBi;
    offC = (long)(z / nCi) * sCo + (long)(z % nCi) * sCi;
  } else {
    const int nwg = (int)gridDim.x;
    const int bid = (int)blockIdx.x;
    const int s = (bid & 7) * (nwg >> 3) + (bid >> 3);
    const int sTile = s >> 4, w = s & 15;
    const int snb = nbn >> 2;
    tm = ((sTile / snb) * 4 + (w >> 2)) * 256;
    tn = ((sTile % snb) * 4 + (w & 3)) * 256;
  }

  const int tid = (int)threadIdx.x;
  const int lane = tid & 63;
  const int wv = tid >> 6;      // 0..7
  const int wm = wv >> 2;       // 0..1 (A half)
  const int wn = wv & 3;        // 0..3
  const int l16 = lane & 15;
  const int kg = lane >> 4;

  // staging: linear LDS dest; content[o] = logical[o ^ ((row&7)<<4)], row=o>>7
  const int srow = tid >> 3;
  const int scolb = ((tid & 7) * 16) ^ (((tid >> 3) & 7) << 4);
  const unsigned short* Abase = A + offA + (long)tm * lda + (scolb >> 1);
  const unsigned short* Bbase = B + offB + (long)tn * ldb + (scolb >> 1);
  const int ldsw = wv * 1024;

  // frag read cols (full-XOR swizzle on byte col, row&7 == l16&7)
  const int colswz0 = (kg * 16) ^ ((l16 & 7) << 4);
  const int colswz1 = (64 + kg * 16) ^ ((l16 & 7) << 4);

  f32x4 acc[8][4];
  #pragma unroll
  for (int i = 0; i < 8; ++i)
    #pragma unroll
    for (int j = 0; j < 4; ++j)
      #pragma unroll
      for (int e = 0; e < 4; ++e) acc[i][j][e] = 0.f;

  auto stageAh = [&](int t, int h) {       // one A half-tile (2 loads)
    const int buf = t & 1;
    #pragma unroll
    for (int i = 0; i < 2; ++i)
      gl_lds16(Abase + (long)(h * 128 + srow + i * 64) * lda + t * 64,
               &LDS[buf * 32768 + h * 16384 + i * 8192 + ldsw]);
  };
  auto stageBh = [&](int t, int h) {       // one B half-tile (2 loads)
    const int buf = t & 1;
    #pragma unroll
    for (int i = 0; i < 2; ++i)
      gl_lds16(Bbase + (long)(h * 128 + srow + i * 64) * ldb + t * 64,
               &LDS[65536 + buf * 32768 + h * 16384 + i * 8192 + ldsw]);
  };

  // prologue: tiles 0,1 staged (8 loads each); wait tile 0 only
  stageAh(0, 0); stageAh(0, 1); stageBh(0, 0); stageBh(0, 1);
  stageAh(1, 0); stageAh(1, 1); stageBh(1, 0); stageBh(1, 1);
  asm volatile("s_waitcnt vmcnt(8)" ::: "memory");
  __builtin_amdgcn_s_barrier();

  // Hazard ledger (2 barriers/tile):
  //  - Each phase: lgkmcnt(0) drains the wave's OWN ds_reads before MFMA.
  //  - j1-end barrier: all waves' j0 B(t)-reads drained (their j0 lgkm)
  //    BEFORE any wave's j2 stageB(t+2) DMA targets B(t)'s slot.
  //  - tile-end vmcnt(4)+barrier: every wave drains through tile t+1's
  //    loads (FIFO: B(t+1)4 A(t+1)4 | B(t+2)4 -> vmcnt(4)); barrier makes
  //    all waves' DMA visible before any wave reads tile t+1. Also orders
  //    last A(old-buf) reads (drained at j3 lgkm) before next j0 stageA.
  for (int t = 0; t < NT; ++t) {
    const unsigned char* aB = &LDS[(t & 1) * 32768 + wm * 16384];
    const unsigned char* bB = &LDS[65536 + (t & 1) * 32768 + (wn >> 1) * 16384];
    const int brow = (wn & 1) * 64;
    bf16x8 bfrag[4][2];
    #pragma unroll
    for (int j = 0; j < 4; ++j) {
      // ds-load this quadrant's A rows
      bf16x8 a0k0 = *(const bf16x8*)(aB + ((2 * j + 0) * 16 + l16) * 128 + colswz0);
      bf16x8 a0k1 = *(const bf16x8*)(aB + ((2 * j + 0) * 16 + l16) * 128 + colswz1);
      bf16x8 a1k0 = *(const bf16x8*)(aB + ((2 * j + 1) * 16 + l16) * 128 + colswz0);
      bf16x8 a1k1 = *(const bf16x8*)(aB + ((2 * j + 1) * 16 + l16) * 128 + colswz1);
      if (j == 0) {
        #pragma unroll
        for (int ni = 0; ni < 4; ++ni) {
          bfrag[ni][0] = *(const bf16x8*)(bB + (brow + ni * 16 + l16) * 128 + colswz0);
          bfrag[ni][1] = *(const bf16x8*)(bB + (brow + ni * 16 + l16) * 128 + colswz1);
        }
        if (t > 0 && t + 1 < NT) stageAh(t + 1, 0);
      } else if (j == 1) {
        if (t > 0 && t + 1 < NT) stageAh(t + 1, 1);
      } else if (j == 2) {
        if (t + 2 < NT) stageBh(t + 2, 0);
      } else {
        if (t + 2 < NT) stageBh(t + 2, 1);
      }
      asm volatile("s_waitcnt lgkmcnt(0)" ::: "memory");
      __builtin_amdgcn_sched_barrier(0);
      __builtin_amdgcn_s_setprio(1);
      #pragma unroll
      for (int ni = 0; ni < 4; ++ni) {
        acc[2 * j + 0][ni] = __builtin_amdgcn_mfma_f32_16x16x32_bf16(a0k0, bfrag[ni][0], acc[2 * j + 0][ni], 0, 0, 0);
        acc[2 * j + 0][ni] = __builtin_amdgcn_mfma_f32_16x16x32_bf16(a0k1, bfrag[ni][1], acc[2 * j + 0][ni], 0, 0, 0);
        acc[2 * j + 1][ni] = __builtin_amdgcn_mfma_f32_16x16x32_bf16(a1k0, bfrag[ni][0], acc[2 * j + 1][ni], 0, 0, 0);
        acc[2 * j + 1][ni] = __builtin_amdgcn_mfma_f32_16x16x32_bf16(a1k1, bfrag[ni][1], acc[2 * j + 1][ni], 0, 0, 0);
      }
      __builtin_amdgcn_s_setprio(0);
      if (j == 1) {
        __builtin_amdgcn_s_barrier();          // protect B(t) slot before j2 stage
      } else if (j == 3) {
        if (t >= NT - 2) { asm volatile("s_waitcnt vmcnt(0)" ::: "memory"); }
        else             { asm volatile("s_waitcnt vmcnt(4)" ::: "memory"); }
        __builtin_amdgcn_sched_barrier(0);
        __builtin_amdgcn_s_barrier();          // tile boundary
      }
    }
  }
  // last tile-end barrier passed: all waves' ds_reads drained -> LDS reusable

  // epilogue
  const int which = SPLIT3 ? (tn >> 12) : 0;
  const float* bp = SPLIT3 ? (which == 0 ? b0 : (which == 1 ? b1 : b2)) : b0;
  void* Cp = SPLIT3 ? (which == 0 ? C0 : (which == 1 ? C1 : C2)) : C0;
  const int tnn = SPLIT3 ? (tn & 4095) : tn;

  if (CF32) {
    // f32 path (final GEMM only): direct stores
    #pragma unroll
    for (int ni = 0; ni < 4; ++ni) {
      const int col = tnn + wn * 64 + ni * 16 + l16;
      const float bv = HAS_BIAS ? bp[col] : 0.f;
      #pragma unroll
      for (int mi = 0; mi < 8; ++mi)
        #pragma unroll
        for (int jj = 0; jj < 4; ++jj) {
          const int row = tm + wm * 128 + mi * 16 + kg * 4 + jj;
          ((float*)Cp)[offC + (long)row * ldc + col] = acc[mi][ni][jj] * alpha + bv;
        }
    }
  } else {
    // bf16 path: per-wave LDS transpose -> fully coalesced 128B row segments
    unsigned short* lw = (unsigned short*)&LDS[wv * 16384];  // private 16KB
    #pragma unroll
    for (int ni = 0; ni < 4; ++ni) {
      const float bv = HAS_BIAS ? bp[tnn + wn * 64 + ni * 16 + l16] : 0.f;
      #pragma unroll
      for (int mi = 0; mi < 8; ++mi)
        #pragma unroll
        for (int jj = 0; jj < 4; ++jj)
          lw[(mi * 16 + kg * 4 + jj) * 64 + ni * 16 + l16] =
              f2bf(acc[mi][ni][jj] * alpha + bv);
    }
    asm volatile("s_waitcnt lgkmcnt(0)" ::: "memory");
    __builtin_amdgcn_sched_barrier(0);
    unsigned short* Cg = (unsigned short*)Cp + offC +
                         (long)(tm + wm * 128) * ldc + tnn + wn * 64;
    const int rr = lane >> 3, cc = (lane & 7) * 8;
    #pragma unroll
    for (int i = 0; i < 16; ++i) {
      short8 val = *(const short8*)&lw[(i * 8 + rr) * 64 + cc];
      *(short8*)(Cg + (long)(i * 8 + rr) * ldc + cc) = val;
    }
  }
}

// ============================================================================
// f32 -> bf16 convert (vectorized, grid-stride), n8 = n/8
// ============================================================================
__global__ __launch_bounds__(256)
void cvt_bf16(const float* __restrict__ in, unsigned short* __restrict__ out, long n8)
{
  long i = (long)blockIdx.x * 256 + threadIdx.x;
  const long stride = (long)gridDim.x * 256;
  for (; i < n8; i += stride) {
    f32x4 v0 = *(const f32x4*)(in + i * 8);
    f32x4 v1 = *(const f32x4*)(in + i * 8 + 4);
    uint4v o;
    o[0] = cvt_pk_bf16(v0[0], v0[1]);
    o[1] = cvt_pk_bf16(v0[2], v0[3]);
    o[2] = cvt_pk_bf16(v1[0], v1[1]);
    o[3] = cvt_pk_bf16(v1[2], v1[3]);
    *(uint4v*)(out + i * 8) = o;
  }
}

// In-place LayerNorm over rows of 512 bf16. One wave/row. g,b f32.
__global__ __launch_bounds__(256)
void ln_rows(unsigned short* __restrict__ t, const float* __restrict__ g,
             const float* __restrict__ b)
{
  const int row = blockIdx.x * 4 + ((int)threadIdx.x >> 6);
  const int lane = (int)threadIdx.x & 63;
  unsigned short* p = t + (long)row * 512 + lane * 8;
  short8 rv = *(const short8*)p;
  float x[8];
  #pragma unroll
  for (int j = 0; j < 8; ++j) x[j] = bf2f((unsigned short)rv[j]);
  float s = 0.f;
  #pragma unroll
  for (int j = 0; j < 8; ++j) s += x[j];
  #pragma unroll
  for (int off = 32; off > 0; off >>= 1) s += __shfl_xor(s, off, 64);
  float mu = s * (1.f / 512.f);
  float vs = 0.f;
  #pragma unroll
  for (int j = 0; j < 8; ++j) { float d = x[j] - mu; vs += d * d; }
  #pragma unroll
  for (int off = 32; off > 0; off >>= 1) vs += __shfl_xor(vs, off, 64);
  float rs = rsqrtf(vs * (1.f / 512.f) + 1e-5f);
  f32x4 gv0 = *(const f32x4*)(g + lane * 8);
  f32x4 gv1 = *(const f32x4*)(g + lane * 8 + 4);
  f32x4 bv0 = *(const f32x4*)(b + lane * 8);
  f32x4 bv1 = *(const f32x4*)(b + lane * 8 + 4);
  short8 ov;
  #pragma unroll
  for (int j = 0; j < 4; ++j) ov[j] = (short)f2bf((x[j] - mu) * rs * gv0[j] + bv0[j]);
  #pragma unroll
  for (int j = 0; j < 4; ++j) ov[4 + j] = (short)f2bf((x[4 + j] - mu) * rs * gv1[j] + bv1[j]);
  *(short8*)p = ov;
}

// w = (val * gelu_exact(gate)) / max(||.||2, 1e-12); h rows are 1024 (val|gate)
__global__ __launch_bounds__(256)
void gate_norm(const unsigned short* __restrict__ h, unsigned short* __restrict__ w)
{
  const int row = blockIdx.x * 4 + ((int)threadIdx.x >> 6);
  const int lane = (int)threadIdx.x & 63;
  const unsigned short* hp = h + (long)row * 1024 + lane * 8;
  short8 vv = *(const short8*)hp;
  short8 gg = *(const short8*)(hp + 512);
  float wv[8];
  float ssq = 0.f;
  #pragma unroll
  for (int j = 0; j < 8; ++j) {
    float val = bf2f((unsigned short)vv[j]);
    float gt  = bf2f((unsigned short)gg[j]);
    float tt  = val * (0.5f * gt * (1.f + erff(gt * 0.70710678118654752f)));
    wv[j] = tt;
    ssq += tt * tt;
  }
  #pragma unroll
  for (int off = 32; off > 0; off >>= 1) ssq += __shfl_xor(ssq, off, 64);
  float scale = 1.f / fmaxf(sqrtf(ssq), 1e-12f);
  short8 ov;
  #pragma unroll
  for (int j = 0; j < 8; ++j) ov[j] = (short)f2bf(wv[j] * scale);
  *(short8*)(w + (long)row * 512 + lane * 8) = ov;
}

// v (B,S,E) bf16 -> vT (B*H, 512d, 512t)
__global__ __launch_bounds__(256)
void transpose_v(const unsigned short* __restrict__ v, unsigned short* __restrict__ vT)
{
  __shared__ alignas(16) unsigned short lt[64][72];
  const int bh = blockIdx.z;
  const int b = bh >> 3, hh = bh & 7;
  const int d0 = blockIdx.x * 64, t0 = blockIdx.y * 64;
  const int tid = (int)threadIdx.x;
  const unsigned short* src = v + (long)b * (512L * 4096L) + hh * 512;
  #pragma unroll
  for (int it = 0; it < 2; ++it) {
    int ci = it * 256 + tid;
    int r = ci >> 3, c8 = (ci & 7) * 8;
    *(short8*)&lt[r][c8] = *(const short8*)(src + (long)(t0 + r) * 4096 + d0 + c8);
  }
  __syncthreads();
  unsigned short* dst = vT + ((long)bh * 512 + d0) * 512 + t0;
  #pragma unroll
  for (int it = 0; it < 2; ++it) {
    int ci = it * 256 + tid;
    int rr = ci >> 3, c8 = (ci & 7) * 8;
    short8 o;
    #pragma unroll
    for (int j = 0; j < 8; ++j) o[j] = (short)lt[c8 + j][rr];
    *(short8*)(dst + (long)rr * 512 + c8) = o;
  }
}

extern "C" void kernel_launch(void* const* d_in, const int* in_sizes, int n_in,
                              void* d_out, int out_size, void* d_ws, size_t ws_size,
                              hipStream_t stream)
{
  (void)in_sizes; (void)n_in; (void)out_size; (void)ws_size;
  const float* x   = (const float*)d_in[0];
  const float* Wq  = (const float*)d_in[1];
  const float* bq  = (const float*)d_in[2];
  const float* Wk  = (const float*)d_in[3];
  const float* bk  = (const float*)d_in[4];
  const float* Wv  = (const float*)d_in[5];
  const float* bv  = (const float*)d_in[6];
  const float* g_q = (const float*)d_in[7];
  const float* b_q = (const float*)d_in[8];
  const float* g_k = (const float*)d_in[9];
  const float* b_k = (const float*)d_in[10];
  const float* Wg  = (const float*)d_in[11];
  const float* bg  = (const float*)d_in[12];
  const float* Wo  = (const float*)d_in[13];
  const float* bo  = (const float*)d_in[14];
  float* out = (float*)d_out;

  const long NE  = 33554432L;   // B*S*E
  const long NE2 = NE / 2;      // 4096*4096
  unsigned short* ws    = (unsigned short*)d_ws;
  unsigned short* xb    = ws;                    // NE
  unsigned short* Wqkv  = ws + NE;               // 1.5*NE (Wq|Wk|Wv rows)
  unsigned short* qbuf  = ws + NE + 3 * NE2;     // NE
  unsigned short* kbuf  = qbuf + NE;             // NE
  unsigned short* vbuf  = kbuf + NE;             // NE
  unsigned short* Wgb   = Wqkv;                  // 1024x512 (after proj)
  unsigned short* Wob   = Wqkv + 524288;         // 4096x4096 (after proj)
  unsigned short* sbuf  = xb;                    // scores (x dead)
  unsigned short* vT    = qbuf;                  // q dead after scores
  unsigned short* hbuf  = kbuf;                  // spans kbuf+vbuf, both dead
  unsigned short* wbuf  = xb;                    // scores dead after h-GEMM
  unsigned short* obuf  = kbuf;                  // h dead after gate_norm

  dim3 blk256(256), blk512(512);
  const float isq = 0.044194173824159216f;  // 1/sqrt(512)

  cvt_bf16<<<16384, blk256, 0, stream>>>(x, xb, NE / 8);
  cvt_bf16<<<8192, blk256, 0, stream>>>(Wq, Wqkv, NE2 / 8);
  cvt_bf16<<<8192, blk256, 0, stream>>>(Wk, Wqkv + NE2, NE2 / 8);
  cvt_bf16<<<8192, blk256, 0, stream>>>(Wv, Wqkv + 2 * NE2, NE2 / 8);

  // merged q|k|v projection: (8192 x 12288) = xb @ Wqkv^T, split-3 epilogue
  gemm256<0, 1, 0, 1><<<1536, blk512, 0, stream>>>(
      xb, Wqkv, bq, bk, bv, qbuf, kbuf, vbuf,
      4096, 4096, 4096, 4096, 48, 1.f,
      0L, 0L, 1, 0L, 0L, 1, 0L, 0L, 1);

  // Wqkv dead -> convert Wg, Wo into its region
  cvt_bf16<<<256, blk256, 0, stream>>>(Wg, Wgb, 524288L / 8);
  cvt_bf16<<<8192, blk256, 0, stream>>>(Wo, Wob, NE2 / 8);

  ln_rows<<<16384, blk256, 0, stream>>>(qbuf, g_q, b_q);
  ln_rows<<<16384, blk256, 0, stream>>>(kbuf, g_k, b_k);

  // scores = q @ k^T / sqrt(HD), per (b,h) -> sbuf (=xb)
  gemm256<1, 0, 0, 0><<<dim3(4, 1, 128), blk512, 0, stream>>>(
      qbuf, kbuf, nullptr, nullptr, nullptr, sbuf, nullptr, nullptr,
      512, 4096, 4096, 512, 2, isq,
      2097152L, 512L, 8,
      2097152L, 512L, 8,
      262144L, 0L, 1);

  transpose_v<<<dim3(8, 8, 128), blk256, 0, stream>>>(vbuf, vT);

  // h = scores @ Wg^T + bg -> hbuf (=kbuf..vbuf)
  gemm256<1, 0, 0, 1><<<dim3(8, 1, 128), blk512, 0, stream>>>(
      sbuf, Wgb, bg, nullptr, nullptr, hbuf, nullptr, nullptr,
      512, 512, 512, 1024, 4, 1.f,
      262144L, 0L, 1,
      0L, 0L, 1,
      524288L, 0L, 1);

  gate_norm<<<16384, blk256, 0, stream>>>(hbuf, wbuf);

  // attn_out = w @ vT^T -> obuf, (B,S,E) layout
  gemm256<1, 0, 0, 0><<<dim3(4, 1, 128), blk512, 0, stream>>>(
      wbuf, vT, nullptr, nullptr, nullptr, obuf, nullptr, nullptr,
      512, 512, 512, 4096, 2, 1.f,
      262144L, 0L, 1,
      262144L, 0L, 1,
      2097152L, 512L, 8);

  // final = attn_out @ Wo^T + bo -> d_out (f32)
  gemm256<0, 0, 1, 1><<<512, blk512, 0, stream>>>(
      obuf, Wob, bo, nullptr, nullptr, out, nullptr, nullptr,
      4096, 4096, 4096, 4096, 16, 1.f,
      0L, 0L, 1, 0L, 0L, 1, 0L, 0L, 1);
}

// Round 10
// 1292.719 us; speedup vs baseline: 1.0608x; 1.0023x over previous
//
#include <hip/hip_runtime.h>
#include <math.h>

typedef __bf16 bf16x8 __attribute__((ext_vector_type(8)));
typedef float f32x4 __attribute__((ext_vector_type(4)));
typedef short short8 __attribute__((ext_vector_type(8)));
typedef unsigned int uint4v __attribute__((ext_vector_type(4)));

__device__ __forceinline__ float bf2f(unsigned short u) {
  union { unsigned int i; float f; } v; v.i = ((unsigned int)u) << 16; return v.f;
}
__device__ __forceinline__ unsigned short f2bf(float f) {
  union { float fl; unsigned int i; } v; v.fl = f;
  unsigned int x = v.i;
  return (unsigned short)((x + 0x7FFFu + ((x >> 16) & 1u)) >> 16);  // RNE
}
__device__ __forceinline__ unsigned int cvt_pk_bf16(float lo, float hi) {
  unsigned int r;
  asm("v_cvt_pk_bf16_f32 %0, %1, %2" : "=v"(r) : "v"(lo), "v"(hi));
  return r;
}
// async global->LDS, 16B per lane. lds ptr wave-uniform (HW adds lane*16).
__device__ __forceinline__ void gl_lds16(const unsigned short* g, void* l) {
  __builtin_amdgcn_global_load_lds(
      (const __attribute__((address_space(1))) unsigned int*)g,
      (__attribute__((address_space(3))) unsigned int*)l, 16, 0, 0);
}

// ============================================================================
// 256x256 bf16 GEMM, 16x16x32 MFMA. R10: minimal barriers (2/tile) + A-frag
// single-phase LOOKAHEAD with counted lgkmcnt(4) — each phase issues next
// phase's 4 A ds_reads, MFMAs on regs loaded last phase (per-wave in-order
// DS FIFO, proven by R5 correctness). afE/afO named sets (+16 VGPR only).
// A/B double-buffered 128KB LDS, counted vmcnt, 0 K-loop bank conflicts,
// LDS-transpose bf16 epilogue.
//  BATCH=0: 1D grid, XCD-chunked + 4x4 super-tiled mapping. BATCH=1: batched.
//  SPLIT3: N spans 3 concatenated 4096-col groups (bias/output per tn>>12).
// ============================================================================
template<int BATCH, int SPLIT3, int CF32, int HAS_BIAS>
__global__ __launch_bounds__(512)
void gemm256(const unsigned short* __restrict__ A,
             const unsigned short* __restrict__ B,
             const float* __restrict__ b0, const float* __restrict__ b1,
             const float* __restrict__ b2,
             void* __restrict__ C0, void* __restrict__ C1, void* __restrict__ C2,
             int K, int lda, int ldb, int ldc, int nbn, float alpha,
             long sAo, long sAi, int nAi,
             long sBo, long sBi, int nBi,
             long sCo, long sCi, int nCi)
{
  __shared__ alignas(16) unsigned char LDS[131072];
  const int NT = K >> 6;   // even, >= 2

  int tm, tn;
  long offA = 0, offB = 0, offC = 0;
  if (BATCH) {
    const int bx = (int)blockIdx.x;
    tm = (bx / nbn) * 256;
    tn = (bx % nbn) * 256;
    const int z = (int)blockIdx.z;
    offA = (long)(z / nAi) * sAo + (long)(z % nAi) * sAi;
    offB = (long)(z / nBi) * sBo + (long)(z % nBi) * sBi;
    offC = (long)(z / nCi) * sCo + (long)(z % nCi) * sCi;
  } else {
    const int nwg = (int)gridDim.x;
    const int bid = (int)blockIdx.x;
    const int s = (bid & 7) * (nwg >> 3) + (bid >> 3);
    const int sTile = s >> 4, w = s & 15;
    const int snb = nbn >> 2;
    tm = ((sTile / snb) * 4 + (w >> 2)) * 256;
    tn = ((sTile % snb) * 4 + (w & 3)) * 256;
  }

  const int tid = (int)threadIdx.x;
  const int lane = tid & 63;
  const int wv = tid >> 6;      // 0..7
  const int wm = wv >> 2;       // 0..1 (A half)
  const int wn = wv & 3;        // 0..3
  const int l16 = lane & 15;
  const int kg = lane >> 4;

  // staging: linear LDS dest; content[o] = logical[o ^ ((row&7)<<4)], row=o>>7
  const int srow = tid >> 3;
  const int scolb = ((tid & 7) * 16) ^ (((tid >> 3) & 7) << 4);
  const unsigned short* Abase = A + offA + (long)tm * lda + (scolb >> 1);
  const unsigned short* Bbase = B + offB + (long)tn * ldb + (scolb >> 1);
  const int ldsw = wv * 1024;

  // frag read cols (full-XOR swizzle on byte col, row&7 == l16&7)
  const int colswz0 = (kg * 16) ^ ((l16 & 7) << 4);
  const int colswz1 = (64 + kg * 16) ^ ((l16 & 7) << 4);

  f32x4 acc[8][4];
  #pragma unroll
  for (int i = 0; i < 8; ++i)
    #pragma unroll
    for (int j = 0; j < 4; ++j)
      #pragma unroll
      for (int e = 0; e < 4; ++e) acc[i][j][e] = 0.f;

  auto stageAh = [&](int t, int h) {       // one A half-tile (2 loads)
    const int buf = t & 1;
    #pragma unroll
    for (int i = 0; i < 2; ++i)
      gl_lds16(Abase + (long)(h * 128 + srow + i * 64) * lda + t * 64,
               &LDS[buf * 32768 + h * 16384 + i * 8192 + ldsw]);
  };
  auto stageBh = [&](int t, int h) {       // one B half-tile (2 loads)
    const int buf = t & 1;
    #pragma unroll
    for (int i = 0; i < 2; ++i)
      gl_lds16(Bbase + (long)(h * 128 + srow + i * 64) * ldb + t * 64,
               &LDS[65536 + buf * 32768 + h * 16384 + i * 8192 + ldsw]);
  };

  // prologue: tiles 0,1 staged (8 loads each); wait tile 0 only
  stageAh(0, 0); stageAh(0, 1); stageBh(0, 0); stageBh(0, 1);
  stageAh(1, 0); stageAh(1, 1); stageBh(1, 0); stageBh(1, 1);
  asm volatile("s_waitcnt vmcnt(8)" ::: "memory");
  __builtin_amdgcn_s_barrier();

  bf16x8 afE[2][2], afO[2][2];   // A frag sets: even/odd phase (rows-pair x k-half)
  bf16x8 bfrag[4][2];

#define LOADA(SET, RB, BASE)                                                      \
  SET[0][0] = *(const bf16x8*)((BASE) + (((RB) + 0) * 16 + l16) * 128 + colswz0); \
  SET[0][1] = *(const bf16x8*)((BASE) + (((RB) + 0) * 16 + l16) * 128 + colswz1); \
  SET[1][0] = *(const bf16x8*)((BASE) + (((RB) + 1) * 16 + l16) * 128 + colswz0); \
  SET[1][1] = *(const bf16x8*)((BASE) + (((RB) + 1) * 16 + l16) * 128 + colswz1);

#define MFMA8(R0, SET)                                                            \
  _Pragma("unroll")                                                               \
  for (int ni = 0; ni < 4; ++ni) {                                                \
    acc[R0][ni] = __builtin_amdgcn_mfma_f32_16x16x32_bf16(SET[0][0], bfrag[ni][0], acc[R0][ni], 0, 0, 0);         \
    acc[R0][ni] = __builtin_amdgcn_mfma_f32_16x16x32_bf16(SET[0][1], bfrag[ni][1], acc[R0][ni], 0, 0, 0);         \
    acc[R0 + 1][ni] = __builtin_amdgcn_mfma_f32_16x16x32_bf16(SET[1][0], bfrag[ni][0], acc[R0 + 1][ni], 0, 0, 0); \
    acc[R0 + 1][ni] = __builtin_amdgcn_mfma_f32_16x16x32_bf16(SET[1][1], bfrag[ni][1], acc[R0 + 1][ni], 0, 0, 0); \
  }

  // preload phase-0 A frags of tile 0 (4 ds_reads left outstanding into j0)
  { const unsigned char* aB0 = &LDS[wm * 16384]; LOADA(afE, 0, aB0) }

  // Ledger per tile t (per-wave DS FIFO; lgkm counts DS ops):
  //  j0: issue B(t)8 + afO(ph1)4 -> FIFO [afE4,B8,afO4]; lgkm(4) drains
  //      afE+B (B(t) drained HERE, per-wave) -> MFMA ph0 on afE.
  //  j1: issue afE(ph2)4; lgkm(4) drains afO(ph1) -> MFMA ph1. BARRIER
  //      (all waves past j0's B-drain before any j2 stageB DMA).
  //  j2: issue afO(ph3)4; lgkm(4) drains afE(ph2) -> MFMA ph2.
  //  j3: lgkm(0) drains afO(ph3) -> MFMA ph3; vmcnt(4) (FIFO: B(t+1)4
  //      A(t+1)4 | B(t+2)4); BARRIER (DMA visibility); then preload
  //      afE(ph0, t+1) from just-drained buffer.
  for (int t = 0; t < NT; ++t) {
    const unsigned char* aB = &LDS[(t & 1) * 32768 + wm * 16384];
    const unsigned char* bB = &LDS[65536 + (t & 1) * 32768 + (wn >> 1) * 16384];
    const int brow = (wn & 1) * 64;

    // ---- j0 ----
    #pragma unroll
    for (int ni = 0; ni < 4; ++ni) {
      bfrag[ni][0] = *(const bf16x8*)(bB + (brow + ni * 16 + l16) * 128 + colswz0);
      bfrag[ni][1] = *(const bf16x8*)(bB + (brow + ni * 16 + l16) * 128 + colswz1);
    }
    LOADA(afO, 2, aB)
    if (t > 0 && t + 1 < NT) stageAh(t + 1, 0);
    asm volatile("s_waitcnt lgkmcnt(4)" ::: "memory");
    __builtin_amdgcn_sched_barrier(0);
    __builtin_amdgcn_s_setprio(1);
    MFMA8(0, afE)
    __builtin_amdgcn_s_setprio(0);

    // ---- j1 ----
    LOADA(afE, 4, aB)
    if (t > 0 && t + 1 < NT) stageAh(t + 1, 1);
    asm volatile("s_waitcnt lgkmcnt(4)" ::: "memory");
    __builtin_amdgcn_sched_barrier(0);
    __builtin_amdgcn_s_setprio(1);
    MFMA8(2, afO)
    __builtin_amdgcn_s_setprio(0);
    __builtin_amdgcn_s_barrier();            // protect B(t) slot before j2 stage

    // ---- j2 ----
    LOADA(afO, 6, aB)
    if (t + 2 < NT) stageBh(t + 2, 0);
    asm volatile("s_waitcnt lgkmcnt(4)" ::: "memory");
    __builtin_amdgcn_sched_barrier(0);
    __builtin_amdgcn_s_setprio(1);
    MFMA8(4, afE)
    __builtin_amdgcn_s_setprio(0);

    // ---- j3 ----
    if (t + 2 < NT) stageBh(t + 2, 1);
    asm volatile("s_waitcnt lgkmcnt(0)" ::: "memory");
    __builtin_amdgcn_sched_barrier(0);
    __builtin_amdgcn_s_setprio(1);
    MFMA8(6, afO)
    __builtin_amdgcn_s_setprio(0);
    if (t >= NT - 2) { asm volatile("s_waitcnt vmcnt(0)" ::: "memory"); }
    else             { asm volatile("s_waitcnt vmcnt(4)" ::: "memory"); }
    __builtin_amdgcn_sched_barrier(0);
    __builtin_amdgcn_s_barrier();            // tile boundary (DMA visibility)
    if (t + 1 < NT) {
      const unsigned char* naB = &LDS[((t + 1) & 1) * 32768 + wm * 16384];
      LOADA(afE, 0, naB)
    }
  }
#undef LOADA
#undef MFMA8
  asm volatile("s_waitcnt lgkmcnt(0)" ::: "memory");  // (no trailing reads issued)

  // epilogue
  const int which = SPLIT3 ? (tn >> 12) : 0;
  const float* bp = SPLIT3 ? (which == 0 ? b0 : (which == 1 ? b1 : b2)) : b0;
  void* Cp = SPLIT3 ? (which == 0 ? C0 : (which == 1 ? C1 : C2)) : C0;
  const int tnn = SPLIT3 ? (tn & 4095) : tn;

  if (CF32) {
    // f32 path (final GEMM only): direct stores
    #pragma unroll
    for (int ni = 0; ni < 4; ++ni) {
      const int col = tnn + wn * 64 + ni * 16 + l16;
      const float bv = HAS_BIAS ? bp[col] : 0.f;
      #pragma unroll
      for (int mi = 0; mi < 8; ++mi)
        #pragma unroll
        for (int jj = 0; jj < 4; ++jj) {
          const int row = tm + wm * 128 + mi * 16 + kg * 4 + jj;
          ((float*)Cp)[offC + (long)row * ldc + col] = acc[mi][ni][jj] * alpha + bv;
        }
    }
  } else {
    // bf16 path: per-wave LDS transpose -> fully coalesced 128B row segments
    unsigned short* lw = (unsigned short*)&LDS[wv * 16384];  // private 16KB
    #pragma unroll
    for (int ni = 0; ni < 4; ++ni) {
      const float bv = HAS_BIAS ? bp[tnn + wn * 64 + ni * 16 + l16] : 0.f;
      #pragma unroll
      for (int mi = 0; mi < 8; ++mi)
        #pragma unroll
        for (int jj = 0; jj < 4; ++jj)
          lw[(mi * 16 + kg * 4 + jj) * 64 + ni * 16 + l16] =
              f2bf(acc[mi][ni][jj] * alpha + bv);
    }
    asm volatile("s_waitcnt lgkmcnt(0)" ::: "memory");
    __builtin_amdgcn_sched_barrier(0);
    unsigned short* Cg = (unsigned short*)Cp + offC +
                         (long)(tm + wm * 128) * ldc + tnn + wn * 64;
    const int rr = lane >> 3, cc = (lane & 7) * 8;
    #pragma unroll
    for (int i = 0; i < 16; ++i) {
      short8 val = *(const short8*)&lw[(i * 8 + rr) * 64 + cc];
      *(short8*)(Cg + (long)(i * 8 + rr) * ldc + cc) = val;
    }
  }
}

// ============================================================================
// f32 -> bf16 convert (vectorized, grid-stride), n8 = n/8
// ============================================================================
__global__ __launch_bounds__(256)
void cvt_bf16(const float* __restrict__ in, unsigned short* __restrict__ out, long n8)
{
  long i = (long)blockIdx.x * 256 + threadIdx.x;
  const long stride = (long)gridDim.x * 256;
  for (; i < n8; i += stride) {
    f32x4 v0 = *(const f32x4*)(in + i * 8);
    f32x4 v1 = *(const f32x4*)(in + i * 8 + 4);
    uint4v o;
    o[0] = cvt_pk_bf16(v0[0], v0[1]);
    o[1] = cvt_pk_bf16(v0[2], v0[3]);
    o[2] = cvt_pk_bf16(v1[0], v1[1]);
    o[3] = cvt_pk_bf16(v1[2], v1[3]);
    *(uint4v*)(out + i * 8) = o;
  }
}

// In-place LayerNorm over rows of 512 bf16. One wave/row. g,b f32.
__global__ __launch_bounds__(256)
void ln_rows(unsigned short* __restrict__ t, const float* __restrict__ g,
             const float* __restrict__ b)
{
  const int row = blockIdx.x * 4 + ((int)threadIdx.x >> 6);
  const int lane = (int)threadIdx.x & 63;
  unsigned short* p = t + (long)row * 512 + lane * 8;
  short8 rv = *(const short8*)p;
  float x[8];
  #pragma unroll
  for (int j = 0; j < 8; ++j) x[j] = bf2f((unsigned short)rv[j]);
  float s = 0.f;
  #pragma unroll
  for (int j = 0; j < 8; ++j) s += x[j];
  #pragma unroll
  for (int off = 32; off > 0; off >>= 1) s += __shfl_xor(s, off, 64);
  float mu = s * (1.f / 512.f);
  float vs = 0.f;
  #pragma unroll
  for (int j = 0; j < 8; ++j) { float d = x[j] - mu; vs += d * d; }
  #pragma unroll
  for (int off = 32; off > 0; off >>= 1) vs += __shfl_xor(vs, off, 64);
  float rs = rsqrtf(vs * (1.f / 512.f) + 1e-5f);
  f32x4 gv0 = *(const f32x4*)(g + lane * 8);
  f32x4 gv1 = *(const f32x4*)(g + lane * 8 + 4);
  f32x4 bv0 = *(const f32x4*)(b + lane * 8);
  f32x4 bv1 = *(const f32x4*)(b + lane * 8 + 4);
  short8 ov;
  #pragma unroll
  for (int j = 0; j < 4; ++j) ov[j] = (short)f2bf((x[j] - mu) * rs * gv0[j] + bv0[j]);
  #pragma unroll
  for (int j = 0; j < 4; ++j) ov[4 + j] = (short)f2bf((x[4 + j] - mu) * rs * gv1[j] + bv1[j]);
  *(short8*)p = ov;
}

// w = (val * gelu_exact(gate)) / max(||.||2, 1e-12); h rows are 1024 (val|gate)
__global__ __launch_bounds__(256)
void gate_norm(const unsigned short* __restrict__ h, unsigned short* __restrict__ w)
{
  const int row = blockIdx.x * 4 + ((int)threadIdx.x >> 6);
  const int lane = (int)threadIdx.x & 63;
  const unsigned short* hp = h + (long)row * 1024 + lane * 8;
  short8 vv = *(const short8*)hp;
  short8 gg = *(const short8*)(hp + 512);
  float wv[8];
  float ssq = 0.f;
  #pragma unroll
  for (int j = 0; j < 8; ++j) {
    float val = bf2f((unsigned short)vv[j]);
    float gt  = bf2f((unsigned short)gg[j]);
    float tt  = val * (0.5f * gt * (1.f + erff(gt * 0.70710678118654752f)));
    wv[j] = tt;
    ssq += tt * tt;
  }
  #pragma unroll
  for (int off = 32; off > 0; off >>= 1) ssq += __shfl_xor(ssq, off, 64);
  float scale = 1.f / fmaxf(sqrtf(ssq), 1e-12f);
  short8 ov;
  #pragma unroll
  for (int j = 0; j < 8; ++j) ov[j] = (short)f2bf(wv[j] * scale);
  *(short8*)(w + (long)row * 512 + lane * 8) = ov;
}

// v (B,S,E) bf16 -> vT (B*H, 512d, 512t)
__global__ __launch_bounds__(256)
void transpose_v(const unsigned short* __restrict__ v, unsigned short* __restrict__ vT)
{
  __shared__ alignas(16) unsigned short lt[64][72];
  const int bh = blockIdx.z;
  const int b = bh >> 3, hh = bh & 7;
  const int d0 = blockIdx.x * 64, t0 = blockIdx.y * 64;
  const int tid = (int)threadIdx.x;
  const unsigned short* src = v + (long)b * (512L * 4096L) + hh * 512;
  #pragma unroll
  for (int it = 0; it < 2; ++it) {
    int ci = it * 256 + tid;
    int r = ci >> 3, c8 = (ci & 7) * 8;
    *(short8*)&lt[r][c8] = *(const short8*)(src + (long)(t0 + r) * 4096 + d0 + c8);
  }
  __syncthreads();
  unsigned short* dst = vT + ((long)bh * 512 + d0) * 512 + t0;
  #pragma unroll
  for (int it = 0; it < 2; ++it) {
    int ci = it * 256 + tid;
    int rr = ci >> 3, c8 = (ci & 7) * 8;
    short8 o;
    #pragma unroll
    for (int j = 0; j < 8; ++j) o[j] = (short)lt[c8 + j][rr];
    *(short8*)(dst + (long)rr * 512 + c8) = o;
  }
}

extern "C" void kernel_launch(void* const* d_in, const int* in_sizes, int n_in,
                              void* d_out, int out_size, void* d_ws, size_t ws_size,
                              hipStream_t stream)
{
  (void)in_sizes; (void)n_in; (void)out_size; (void)ws_size;
  const float* x   = (const float*)d_in[0];
  const float* Wq  = (const float*)d_in[1];
  const float* bq  = (const float*)d_in[2];
  const float* Wk  = (const float*)d_in[3];
  const float* bk  = (const float*)d_in[4];
  const float* Wv  = (const float*)d_in[5];
  const float* bv  = (const float*)d_in[6];
  const float* g_q = (const float*)d_in[7];
  const float* b_q = (const float*)d_in[8];
  const float* g_k = (const float*)d_in[9];
  const float* b_k = (const float*)d_in[10];
  const float* Wg  = (const float*)d_in[11];
  const float* bg  = (const float*)d_in[12];
  const float* Wo  = (const float*)d_in[13];
  const float* bo  = (const float*)d_in[14];
  float* out = (float*)d_out;

  const long NE  = 33554432L;   // B*S*E
  const long NE2 = NE / 2;      // 4096*4096
  unsigned short* ws    = (unsigned short*)d_ws;
  unsigned short* xb    = ws;                    // NE
  unsigned short* Wqkv  = ws + NE;               // 1.5*NE (Wq|Wk|Wv rows)
  unsigned short* qbuf  = ws + NE + 3 * NE2;     // NE
  unsigned short* kbuf  = qbuf + NE;             // NE
  unsigned short* vbuf  = kbuf + NE;             // NE
  unsigned short* Wgb   = Wqkv;                  // 1024x512 (after proj)
  unsigned short* Wob   = Wqkv + 524288;         // 4096x4096 (after proj)
  unsigned short* sbuf  = xb;                    // scores (x dead)
  unsigned short* vT    = qbuf;                  // q dead after scores
  unsigned short* hbuf  = kbuf;                  // spans kbuf+vbuf, both dead
  unsigned short* wbuf  = xb;                    // scores dead after h-GEMM
  unsigned short* obuf  = kbuf;                  // h dead after gate_norm

  dim3 blk256(256), blk512(512);
  const float isq = 0.044194173824159216f;  // 1/sqrt(512)

  cvt_bf16<<<16384, blk256, 0, stream>>>(x, xb, NE / 8);
  cvt_bf16<<<8192, blk256, 0, stream>>>(Wq, Wqkv, NE2 / 8);
  cvt_bf16<<<8192, blk256, 0, stream>>>(Wk, Wqkv + NE2, NE2 / 8);
  cvt_bf16<<<8192, blk256, 0, stream>>>(Wv, Wqkv + 2 * NE2, NE2 / 8);

  // merged q|k|v projection: (8192 x 12288) = xb @ Wqkv^T, split-3 epilogue
  gemm256<0, 1, 0, 1><<<1536, blk512, 0, stream>>>(
      xb, Wqkv, bq, bk, bv, qbuf, kbuf, vbuf,
      4096, 4096, 4096, 4096, 48, 1.f,
      0L, 0L, 1, 0L, 0L, 1, 0L, 0L, 1);

  // Wqkv dead -> convert Wg, Wo into its region
  cvt_bf16<<<256, blk256, 0, stream>>>(Wg, Wgb, 524288L / 8);
  cvt_bf16<<<8192, blk256, 0, stream>>>(Wo, Wob, NE2 / 8);

  ln_rows<<<16384, blk256, 0, stream>>>(qbuf, g_q, b_q);
  ln_rows<<<16384, blk256, 0, stream>>>(kbuf, g_k, b_k);

  // scores = q @ k^T / sqrt(HD), per (b,h) -> sbuf (=xb)
  gemm256<1, 0, 0, 0><<<dim3(4, 1, 128), blk512, 0, stream>>>(
      qbuf, kbuf, nullptr, nullptr, nullptr, sbuf, nullptr, nullptr,
      512, 4096, 4096, 512, 2, isq,
      2097152L, 512L, 8,
      2097152L, 512L, 8,
      262144L, 0L, 1);

  transpose_v<<<dim3(8, 8, 128), blk256, 0, stream>>>(vbuf, vT);

  // h = scores @ Wg^T + bg -> hbuf (=kbuf..vbuf)
  gemm256<1, 0, 0, 1><<<dim3(8, 1, 128), blk512, 0, stream>>>(
      sbuf, Wgb, bg, nullptr, nullptr, hbuf, nullptr, nullptr,
      512, 512, 512, 1024, 4, 1.f,
      262144L, 0L, 1,
      0L, 0L, 1,
      524288L, 0L, 1);

  gate_norm<<<16384, blk256, 0, stream>>>(hbuf, wbuf);

  // attn_out = w @ vT^T -> obuf, (B,S,E) layout
  gemm256<1, 0, 0, 0><<<dim3(4, 1, 128), blk512, 0, stream>>>(
      wbuf, vT, nullptr, nullptr, nullptr, obuf, nullptr, nullptr,
      512, 512, 512, 4096, 2, 1.f,
      262144L, 0L, 1,
      262144L, 0L, 1,
      2097152L, 512L, 8);

  // final = attn_out @ Wo^T + bo -> d_out (f32)
  gemm256<0, 0, 1, 1><<<512, blk512, 0, stream>>>(
      obuf, Wob, bo, nullptr, nullptr, out, nullptr, nullptr,
      4096, 4096, 4096, 4096, 16, 1.f,
      0L, 0L, 1, 0L, 0L, 1, 0L, 0L, 1);
}

// Round 11
// 1234.825 us; speedup vs baseline: 1.1106x; 1.0469x over previous
//
#include <hip/hip_runtime.h>
#include <math.h>

typedef __bf16 bf16x8 __attribute__((ext_vector_type(8)));
typedef float f32x4 __attribute__((ext_vector_type(4)));
typedef short short8 __attribute__((ext_vector_type(8)));
typedef unsigned int uint4v __attribute__((ext_vector_type(4)));

__device__ __forceinline__ float bf2f(unsigned short u) {
  union { unsigned int i; float f; } v; v.i = ((unsigned int)u) << 16; return v.f;
}
__device__ __forceinline__ unsigned short f2bf(float f) {
  union { float fl; unsigned int i; } v; v.fl = f;
  unsigned int x = v.i;
  return (unsigned short)((x + 0x7FFFu + ((x >> 16) & 1u)) >> 16);  // RNE
}
__device__ __forceinline__ unsigned int cvt_pk_bf16(float lo, float hi) {
  unsigned int r;
  asm("v_cvt_pk_bf16_f32 %0, %1, %2" : "=v"(r) : "v"(lo), "v"(hi));
  return r;
}
// async global->LDS, 16B per lane. lds ptr wave-uniform (HW adds lane*16).
__device__ __forceinline__ void gl_lds16(const unsigned short* g, void* l) {
  __builtin_amdgcn_global_load_lds(
      (const __attribute__((address_space(1))) unsigned int*)g,
      (__attribute__((address_space(3))) unsigned int*)l, 16, 0, 0);
}

// ============================================================================
// 256x256 bf16 GEMM, 16x16x32 MFMA, R9-proven minimal-barrier schedule
// (2 barriers/tile, counted vmcnt(4), 0 K-loop bank conflicts).
//  BATCH=0: 1D grid, XCD-chunked + 4x4 super-tiled mapping. BATCH=1: batched.
//  SPLIT3: N spans 3 concatenated 4096-col groups; group 2 (v) is written
//          TRANSPOSED into vT (B*H, 512d, 512t) — fuses transpose_v.
// ============================================================================
template<int BATCH, int SPLIT3, int CF32, int HAS_BIAS>
__global__ __launch_bounds__(512)
void gemm256(const unsigned short* __restrict__ A,
             const unsigned short* __restrict__ B,
             const float* __restrict__ b0, const float* __restrict__ b1,
             const float* __restrict__ b2,
             void* __restrict__ C0, void* __restrict__ C1, void* __restrict__ C2,
             int K, int lda, int ldb, int ldc, int nbn, float alpha,
             long sAo, long sAi, int nAi,
             long sBo, long sBi, int nBi,
             long sCo, long sCi, int nCi)
{
  __shared__ alignas(16) unsigned char LDS[131072];
  const int NT = K >> 6;   // even, >= 2

  int tm, tn;
  long offA = 0, offB = 0, offC = 0;
  if (BATCH) {
    const int bx = (int)blockIdx.x;
    tm = (bx / nbn) * 256;
    tn = (bx % nbn) * 256;
    const int z = (int)blockIdx.z;
    offA = (long)(z / nAi) * sAo + (long)(z % nAi) * sAi;
    offB = (long)(z / nBi) * sBo + (long)(z % nBi) * sBi;
    offC = (long)(z / nCi) * sCo + (long)(z % nCi) * sCi;
  } else {
    const int nwg = (int)gridDim.x;
    const int bid = (int)blockIdx.x;
    const int s = (bid & 7) * (nwg >> 3) + (bid >> 3);
    const int sTile = s >> 4, w = s & 15;
    const int snb = nbn >> 2;
    tm = ((sTile / snb) * 4 + (w >> 2)) * 256;
    tn = ((sTile % snb) * 4 + (w & 3)) * 256;
  }

  const int tid = (int)threadIdx.x;
  const int lane = tid & 63;
  const int wv = tid >> 6;      // 0..7
  const int wm = wv >> 2;       // 0..1 (A half)
  const int wn = wv & 3;        // 0..3
  const int l16 = lane & 15;
  const int kg = lane >> 4;

  // staging: linear LDS dest; content[o] = logical[o ^ ((row&7)<<4)], row=o>>7
  const int srow = tid >> 3;
  const int scolb = ((tid & 7) * 16) ^ (((tid >> 3) & 7) << 4);
  const unsigned short* Abase = A + offA + (long)tm * lda + (scolb >> 1);
  const unsigned short* Bbase = B + offB + (long)tn * ldb + (scolb >> 1);
  const int ldsw = wv * 1024;

  // frag read cols (full-XOR swizzle on byte col, row&7 == l16&7)
  const int colswz0 = (kg * 16) ^ ((l16 & 7) << 4);
  const int colswz1 = (64 + kg * 16) ^ ((l16 & 7) << 4);

  f32x4 acc[8][4];
  #pragma unroll
  for (int i = 0; i < 8; ++i)
    #pragma unroll
    for (int j = 0; j < 4; ++j)
      #pragma unroll
      for (int e = 0; e < 4; ++e) acc[i][j][e] = 0.f;

  auto stageAh = [&](int t, int h) {       // one A half-tile (2 loads)
    const int buf = t & 1;
    #pragma unroll
    for (int i = 0; i < 2; ++i)
      gl_lds16(Abase + (long)(h * 128 + srow + i * 64) * lda + t * 64,
               &LDS[buf * 32768 + h * 16384 + i * 8192 + ldsw]);
  };
  auto stageBh = [&](int t, int h) {       // one B half-tile (2 loads)
    const int buf = t & 1;
    #pragma unroll
    for (int i = 0; i < 2; ++i)
      gl_lds16(Bbase + (long)(h * 128 + srow + i * 64) * ldb + t * 64,
               &LDS[65536 + buf * 32768 + h * 16384 + i * 8192 + ldsw]);
  };

  // prologue: tiles 0,1 staged (8 loads each); wait tile 0 only
  stageAh(0, 0); stageAh(0, 1); stageBh(0, 0); stageBh(0, 1);
  stageAh(1, 0); stageAh(1, 1); stageBh(1, 0); stageBh(1, 1);
  asm volatile("s_waitcnt vmcnt(8)" ::: "memory");
  __builtin_amdgcn_s_barrier();

  // Hazard ledger (2 barriers/tile) — see R9; unchanged (proven schedule).
  for (int t = 0; t < NT; ++t) {
    const unsigned char* aB = &LDS[(t & 1) * 32768 + wm * 16384];
    const unsigned char* bB = &LDS[65536 + (t & 1) * 32768 + (wn >> 1) * 16384];
    const int brow = (wn & 1) * 64;
    bf16x8 bfrag[4][2];
    #pragma unroll
    for (int j = 0; j < 4; ++j) {
      bf16x8 a0k0 = *(const bf16x8*)(aB + ((2 * j + 0) * 16 + l16) * 128 + colswz0);
      bf16x8 a0k1 = *(const bf16x8*)(aB + ((2 * j + 0) * 16 + l16) * 128 + colswz1);
      bf16x8 a1k0 = *(const bf16x8*)(aB + ((2 * j + 1) * 16 + l16) * 128 + colswz0);
      bf16x8 a1k1 = *(const bf16x8*)(aB + ((2 * j + 1) * 16 + l16) * 128 + colswz1);
      if (j == 0) {
        #pragma unroll
        for (int ni = 0; ni < 4; ++ni) {
          bfrag[ni][0] = *(const bf16x8*)(bB + (brow + ni * 16 + l16) * 128 + colswz0);
          bfrag[ni][1] = *(const bf16x8*)(bB + (brow + ni * 16 + l16) * 128 + colswz1);
        }
        if (t > 0 && t + 1 < NT) stageAh(t + 1, 0);
      } else if (j == 1) {
        if (t > 0 && t + 1 < NT) stageAh(t + 1, 1);
      } else if (j == 2) {
        if (t + 2 < NT) stageBh(t + 2, 0);
      } else {
        if (t + 2 < NT) stageBh(t + 2, 1);
      }
      asm volatile("s_waitcnt lgkmcnt(0)" ::: "memory");
      __builtin_amdgcn_sched_barrier(0);
      __builtin_amdgcn_s_setprio(1);
      #pragma unroll
      for (int ni = 0; ni < 4; ++ni) {
        acc[2 * j + 0][ni] = __builtin_amdgcn_mfma_f32_16x16x32_bf16(a0k0, bfrag[ni][0], acc[2 * j + 0][ni], 0, 0, 0);
        acc[2 * j + 0][ni] = __builtin_amdgcn_mfma_f32_16x16x32_bf16(a0k1, bfrag[ni][1], acc[2 * j + 0][ni], 0, 0, 0);
        acc[2 * j + 1][ni] = __builtin_amdgcn_mfma_f32_16x16x32_bf16(a1k0, bfrag[ni][0], acc[2 * j + 1][ni], 0, 0, 0);
        acc[2 * j + 1][ni] = __builtin_amdgcn_mfma_f32_16x16x32_bf16(a1k1, bfrag[ni][1], acc[2 * j + 1][ni], 0, 0, 0);
      }
      __builtin_amdgcn_s_setprio(0);
      if (j == 1) {
        __builtin_amdgcn_s_barrier();          // protect B(t) slot before j2 stage
      } else if (j == 3) {
        if (t >= NT - 2) { asm volatile("s_waitcnt vmcnt(0)" ::: "memory"); }
        else             { asm volatile("s_waitcnt vmcnt(4)" ::: "memory"); }
        __builtin_amdgcn_sched_barrier(0);
        __builtin_amdgcn_s_barrier();          // tile boundary
      }
    }
  }
  // last tile-end barrier passed: all waves' ds_reads drained -> LDS reusable

  // epilogue
  const int which = SPLIT3 ? (tn >> 12) : 0;
  const float* bp = SPLIT3 ? (which == 0 ? b0 : (which == 1 ? b1 : b2)) : b0;
  void* Cp = SPLIT3 ? (which == 0 ? C0 : (which == 1 ? C1 : C2)) : C0;
  const int tnn = SPLIT3 ? (tn & 4095) : tn;

  if (CF32) {
    // f32 path (final GEMM): nontemporal direct stores (never re-read)
    #pragma unroll
    for (int ni = 0; ni < 4; ++ni) {
      const int col = tnn + wn * 64 + ni * 16 + l16;
      const float bv = HAS_BIAS ? bp[col] : 0.f;
      #pragma unroll
      for (int mi = 0; mi < 8; ++mi)
        #pragma unroll
        for (int jj = 0; jj < 4; ++jj) {
          const int row = tm + wm * 128 + mi * 16 + kg * 4 + jj;
          __builtin_nontemporal_store(acc[mi][ni][jj] * alpha + bv,
                                      &((float*)Cp)[offC + (long)row * ldc + col]);
        }
    }
  } else if (SPLIT3 && which == 2) {
    // v group: write TRANSPOSED into vT (B*H, 512d, 512t). Per-wave slab holds
    // 64 d x 128 t, swizzled t ^ ((d&7)<<4) to break write-bank collisions.
    unsigned short* lw = (unsigned short*)&LDS[wv * 16384];
    #pragma unroll
    for (int ni = 0; ni < 4; ++ni) {
      const int dl = ni * 16 + l16;
      const float bv = HAS_BIAS ? bp[tnn + wn * 64 + dl] : 0.f;
      #pragma unroll
      for (int mi = 0; mi < 8; ++mi)
        #pragma unroll
        for (int jj = 0; jj < 4; ++jj) {
          const int tl = mi * 16 + kg * 4 + jj;
          lw[dl * 128 + (tl ^ ((dl & 7) << 4))] = f2bf(acc[mi][ni][jj] * alpha + bv);
        }
    }
    asm volatile("s_waitcnt lgkmcnt(0)" ::: "memory");
    __builtin_amdgcn_sched_barrier(0);
    const int b = tm >> 9, hh = tnn >> 9;
    const int dbase = (tnn & 511) + wn * 64;
    const int tbase = (tm & 511) + wm * 128;
    unsigned short* vTg = (unsigned short*)C2 +
                          ((long)(b * 8 + hh) * 512 + dbase) * 512 + tbase;
    const int dr = lane >> 4, t8 = (lane & 15) * 8;
    #pragma unroll
    for (int i = 0; i < 16; ++i) {
      const int dl = i * 4 + dr;
      short8 val = *(const short8*)&lw[dl * 128 + (t8 ^ ((dl & 7) << 4))];
      __builtin_nontemporal_store(val, (short8*)(vTg + (long)dl * 512 + t8));
    }
  } else {
    // bf16 path: per-wave LDS transpose -> fully coalesced 128B row segments
    unsigned short* lw = (unsigned short*)&LDS[wv * 16384];  // private 16KB
    #pragma unroll
    for (int ni = 0; ni < 4; ++ni) {
      const float bv = HAS_BIAS ? bp[tnn + wn * 64 + ni * 16 + l16] : 0.f;
      #pragma unroll
      for (int mi = 0; mi < 8; ++mi)
        #pragma unroll
        for (int jj = 0; jj < 4; ++jj)
          lw[(mi * 16 + kg * 4 + jj) * 64 + ni * 16 + l16] =
              f2bf(acc[mi][ni][jj] * alpha + bv);
    }
    asm volatile("s_waitcnt lgkmcnt(0)" ::: "memory");
    __builtin_amdgcn_sched_barrier(0);
    unsigned short* Cg = (unsigned short*)Cp + offC +
                         (long)(tm + wm * 128) * ldc + tnn + wn * 64;
    const int rr = lane >> 3, cc = (lane & 7) * 8;
    #pragma unroll
    for (int i = 0; i < 16; ++i) {
      short8 val = *(const short8*)&lw[(i * 8 + rr) * 64 + cc];
      *(short8*)(Cg + (long)(i * 8 + rr) * ldc + cc) = val;
    }
  }
}

// ============================================================================
// merged f32 -> bf16 convert over up to 4 consecutive dst ranges
// dst is ONE contiguous region; src selected by element range. n8 = total/8.
// ============================================================================
__global__ __launch_bounds__(256)
void cvt_multi(const float* __restrict__ s0, long n0,
               const float* __restrict__ s1, long n1,
               const float* __restrict__ s2, long n2,
               const float* __restrict__ s3, long n3,
               unsigned short* __restrict__ dst, long n8)
{
  long i = (long)blockIdx.x * 256 + threadIdx.x;
  const long stride = (long)gridDim.x * 256;
  for (; i < n8; i += stride) {
    long e = i * 8;
    const float* src;
    if (e < n0)                    src = s0 + e;
    else if (e < n0 + n1)          src = s1 + (e - n0);
    else if (e < n0 + n1 + n2)     src = s2 + (e - n0 - n1);
    else                           src = s3 + (e - n0 - n1 - n2);
    f32x4 v0 = *(const f32x4*)(src);
    f32x4 v1 = *(const f32x4*)(src + 4);
    uint4v o;
    o[0] = cvt_pk_bf16(v0[0], v0[1]);
    o[1] = cvt_pk_bf16(v0[2], v0[3]);
    o[2] = cvt_pk_bf16(v1[0], v1[1]);
    o[3] = cvt_pk_bf16(v1[2], v1[3]);
    *(uint4v*)(dst + e) = o;
  }
}

// In-place LayerNorm over rows of 512 bf16 for q then k (merged). One wave/row.
__global__ __launch_bounds__(256)
void ln_rows2(unsigned short* __restrict__ q, const float* __restrict__ gq,
              const float* __restrict__ bq_, unsigned short* __restrict__ k,
              const float* __restrict__ gk, const float* __restrict__ bk_,
              int rows_per_tensor)
{
  int row = blockIdx.x * 4 + ((int)threadIdx.x >> 6);
  const int lane = (int)threadIdx.x & 63;
  unsigned short* base = q;
  const float* g = gq;
  const float* b = bq_;
  if (row >= rows_per_tensor) { row -= rows_per_tensor; base = k; g = gk; b = bk_; }
  unsigned short* p = base + (long)row * 512 + lane * 8;
  short8 rv = *(const short8*)p;
  float x[8];
  #pragma unroll
  for (int j = 0; j < 8; ++j) x[j] = bf2f((unsigned short)rv[j]);
  float s = 0.f;
  #pragma unroll
  for (int j = 0; j < 8; ++j) s += x[j];
  #pragma unroll
  for (int off = 32; off > 0; off >>= 1) s += __shfl_xor(s, off, 64);
  float mu = s * (1.f / 512.f);
  float vs = 0.f;
  #pragma unroll
  for (int j = 0; j < 8; ++j) { float d = x[j] - mu; vs += d * d; }
  #pragma unroll
  for (int off = 32; off > 0; off >>= 1) vs += __shfl_xor(vs, off, 64);
  float rs = rsqrtf(vs * (1.f / 512.f) + 1e-5f);
  f32x4 gv0 = *(const f32x4*)(g + lane * 8);
  f32x4 gv1 = *(const f32x4*)(g + lane * 8 + 4);
  f32x4 bv0 = *(const f32x4*)(b + lane * 8);
  f32x4 bv1 = *(const f32x4*)(b + lane * 8 + 4);
  short8 ov;
  #pragma unroll
  for (int j = 0; j < 4; ++j) ov[j] = (short)f2bf((x[j] - mu) * rs * gv0[j] + bv0[j]);
  #pragma unroll
  for (int j = 0; j < 4; ++j) ov[4 + j] = (short)f2bf((x[4 + j] - mu) * rs * gv1[j] + bv1[j]);
  *(short8*)p = ov;
}

// w = (val * gelu_exact(gate)) / max(||.||2, 1e-12); h rows are 1024 (val|gate)
__global__ __launch_bounds__(256)
void gate_norm(const unsigned short* __restrict__ h, unsigned short* __restrict__ w)
{
  const int row = blockIdx.x * 4 + ((int)threadIdx.x >> 6);
  const int lane = (int)threadIdx.x & 63;
  const unsigned short* hp = h + (long)row * 1024 + lane * 8;
  short8 vv = *(const short8*)hp;
  short8 gg = *(const short8*)(hp + 512);
  float wv[8];
  float ssq = 0.f;
  #pragma unroll
  for (int j = 0; j < 8; ++j) {
    float val = bf2f((unsigned short)vv[j]);
    float gt  = bf2f((unsigned short)gg[j]);
    float tt  = val * (0.5f * gt * (1.f + erff(gt * 0.70710678118654752f)));
    wv[j] = tt;
    ssq += tt * tt;
  }
  #pragma unroll
  for (int off = 32; off > 0; off >>= 1) ssq += __shfl_xor(ssq, off, 64);
  float scale = 1.f / fmaxf(sqrtf(ssq), 1e-12f);
  short8 ov;
  #pragma unroll
  for (int j = 0; j < 8; ++j) ov[j] = (short)f2bf(wv[j] * scale);
  *(short8*)(w + (long)row * 512 + lane * 8) = ov;
}

extern "C" void kernel_launch(void* const* d_in, const int* in_sizes, int n_in,
                              void* d_out, int out_size, void* d_ws, size_t ws_size,
                              hipStream_t stream)
{
  (void)in_sizes; (void)n_in; (void)out_size; (void)ws_size;
  const float* x   = (const float*)d_in[0];
  const float* Wq  = (const float*)d_in[1];
  const float* bq  = (const float*)d_in[2];
  const float* Wk  = (const float*)d_in[3];
  const float* bk  = (const float*)d_in[4];
  const float* Wv  = (const float*)d_in[5];
  const float* bv  = (const float*)d_in[6];
  const float* g_q = (const float*)d_in[7];
  const float* b_q = (const float*)d_in[8];
  const float* g_k = (const float*)d_in[9];
  const float* b_k = (const float*)d_in[10];
  const float* Wg  = (const float*)d_in[11];
  const float* bg  = (const float*)d_in[12];
  const float* Wo  = (const float*)d_in[13];
  const float* bo  = (const float*)d_in[14];
  float* out = (float*)d_out;

  const long NE  = 33554432L;   // B*S*E
  const long NE2 = NE / 2;      // 4096*4096
  unsigned short* ws    = (unsigned short*)d_ws;
  unsigned short* xb    = ws;                    // [0, NE)
  unsigned short* Wqkv  = ws + NE;               // [NE, 2.5NE) Wq|Wk|Wv
  unsigned short* qbuf  = ws + NE + 3 * NE2;     // [2.5NE, 3.5NE)
  unsigned short* kbuf  = qbuf + NE;             // [3.5NE, 4.5NE)
  unsigned short* vT    = kbuf + NE;             // [4.5NE, 5.5NE) (B*H,512d,512t)
  unsigned short* Wgb   = Wqkv;                  // 1024x512 (after proj)
  unsigned short* Wob   = Wqkv + 524288;         // 4096x4096 (after proj)
  unsigned short* sbuf  = xb;                    // scores (x dead after proj)
  unsigned short* hbuf  = qbuf;                  // spans qbuf+kbuf (dead after scores)
  unsigned short* wbuf  = xb;                    // scores dead after h-GEMM
  unsigned short* obuf  = kbuf;                  // h dead after gate_norm

  dim3 blk256(256), blk512(512);
  const float isq = 0.044194173824159216f;  // 1/sqrt(512)

  // one merged convert: x | Wq | Wk | Wv  ->  ws[0 .. 2.5NE)
  cvt_multi<<<20480, blk256, 0, stream>>>(x, NE, Wq, NE2, Wk, NE2, Wv, NE2,
                                          ws, (NE + 3 * NE2) / 8);

  // merged q|k|v projection: split-3 epilogue; v written transposed into vT
  gemm256<0, 1, 0, 1><<<1536, blk512, 0, stream>>>(
      xb, Wqkv, bq, bk, bv, qbuf, kbuf, vT,
      4096, 4096, 4096, 4096, 48, 1.f,
      0L, 0L, 1, 0L, 0L, 1, 0L, 0L, 1);

  // Wqkv dead -> convert Wg, Wo into its region (one launch)
  cvt_multi<<<8192, blk256, 0, stream>>>(Wg, 524288L, Wo, NE2,
                                         nullptr, 0L, nullptr, 0L,
                                         Wgb, (524288L + NE2) / 8);

  // layernorm q and k (merged)
  ln_rows2<<<32768, blk256, 0, stream>>>(qbuf, g_q, b_q, kbuf, g_k, b_k, 65536);

  // scores = q @ k^T / sqrt(HD), per (b,h) -> sbuf (=xb)
  gemm256<1, 0, 0, 0><<<dim3(4, 1, 128), blk512, 0, stream>>>(
      qbuf, kbuf, nullptr, nullptr, nullptr, sbuf, nullptr, nullptr,
      512, 4096, 4096, 512, 2, isq,
      2097152L, 512L, 8,
      2097152L, 512L, 8,
      262144L, 0L, 1);

  // h = scores @ Wg^T + bg -> hbuf (=qbuf..kbuf)
  gemm256<1, 0, 0, 1><<<dim3(8, 1, 128), blk512, 0, stream>>>(
      sbuf, Wgb, bg, nullptr, nullptr, hbuf, nullptr, nullptr,
      512, 512, 512, 1024, 4, 1.f,
      262144L, 0L, 1,
      0L, 0L, 1,
      524288L, 0L, 1);

  gate_norm<<<16384, blk256, 0, stream>>>(hbuf, wbuf);

  // attn_out = w @ vT^T -> obuf (=kbuf), (B,S,E) layout
  gemm256<1, 0, 0, 0><<<dim3(4, 1, 128), blk512, 0, stream>>>(
      wbuf, vT, nullptr, nullptr, nullptr, obuf, nullptr, nullptr,
      512, 512, 512, 4096, 2, 1.f,
      262144L, 0L, 1,
      262144L, 0L, 1,
      2097152L, 512L, 8);

  // final = attn_out @ Wo^T + bo -> d_out (f32, nontemporal)
  gemm256<0, 0, 1, 1><<<512, blk512, 0, stream>>>(
      obuf, Wob, bo, nullptr, nullptr, out, nullptr, nullptr,
      4096, 4096, 4096, 4096, 16, 1.f,
      0L, 0L, 1, 0L, 0L, 1, 0L, 0L, 1);
}

// Round 12
// 1210.433 us; speedup vs baseline: 1.1329x; 1.0202x over previous
//
#include <hip/hip_runtime.h>
#include <math.h>

typedef __bf16 bf16x8 __attribute__((ext_vector_type(8)));
typedef float f32x4 __attribute__((ext_vector_type(4)));
typedef short short8 __attribute__((ext_vector_type(8)));
typedef unsigned int uint4v __attribute__((ext_vector_type(4)));

__device__ __forceinline__ float bf2f(unsigned short u) {
  union { unsigned int i; float f; } v; v.i = ((unsigned int)u) << 16; return v.f;
}
__device__ __forceinline__ unsigned short f2bf(float f) {
  union { float fl; unsigned int i; } v; v.fl = f;
  unsigned int x = v.i;
  return (unsigned short)((x + 0x7FFFu + ((x >> 16) & 1u)) >> 16);  // RNE
}
__device__ __forceinline__ unsigned int cvt_pk_bf16(float lo, float hi) {
  unsigned int r;
  asm("v_cvt_pk_bf16_f32 %0, %1, %2" : "=v"(r) : "v"(lo), "v"(hi));
  return r;
}
// async global->LDS, 16B per lane. lds ptr wave-uniform (HW adds lane*16).
__device__ __forceinline__ void gl_lds16(const unsigned short* g, void* l) {
  __builtin_amdgcn_global_load_lds(
      (const __attribute__((address_space(1))) unsigned int*)g,
      (__attribute__((address_space(3))) unsigned int*)l, 16, 0, 0);
}

// ============================================================================
// 256x256 bf16 GEMM, 16x16x32 MFMA. R12: R9 minimal-barrier schedule with
// both barriers moved PRE-MFMA (post-barrier slack = 16 MFMA + next-phase
// ds_reads; pure reorder). Batched mode gets XCD-chunked swizzle (z-major
// flatten) so same-batch tiles share one XCD's L2.
//  SPLIT3: N spans 3 concatenated 4096-col groups; group 2 (v) written
//          TRANSPOSED into vT (B*H, 512d, 512t).
// Hazard ledger (per tile t, 2 barriers, both pre-MFMA):
//  - Each phase: wave's own lgkmcnt(0) drains its ds_reads before its MFMA
//    AND before it can reach the next barrier.
//  - j1 barrier (pre-MFMA8(2)): every wave past it has executed j0's
//    lgkmcnt(0) -> all B(t) frag reads drained before any j2 stageB(t+2)
//    DMA targets B(t)'s slot.
//  - j3 barrier (pre-MFMA8(6), after vmcnt): every wave drained through
//    tile t+1's staging loads (FIFO: B(t+1)4 A(t+1)4 | B(t+2)4 -> vmcnt(4))
//    and through its own A(t)/B(t) ds_reads -> tile t+1 buffers valid and
//    A(t) slot safe for next j0's stageA(t+2).
// ============================================================================
template<int BATCH, int SPLIT3, int CF32, int HAS_BIAS>
__global__ __launch_bounds__(512)
void gemm256(const unsigned short* __restrict__ A,
             const unsigned short* __restrict__ B,
             const float* __restrict__ b0, const float* __restrict__ b1,
             const float* __restrict__ b2,
             void* __restrict__ C0, void* __restrict__ C1, void* __restrict__ C2,
             int K, int lda, int ldb, int ldc, int nbn, float alpha,
             long sAo, long sAi, int nAi,
             long sBo, long sBi, int nBi,
             long sCo, long sCi, int nCi)
{
  __shared__ alignas(16) unsigned char LDS[131072];
  const int NT = K >> 6;   // even, >= 2

  int tm, tn;
  long offA = 0, offB = 0, offC = 0;
  if (BATCH) {
    // XCD-chunked over z-major flatten (total blocks % 8 == 0):
    // consecutive work-items (same batch) land on the same XCD's L2.
    const int nbx = (int)gridDim.x;
    const int nf = nbx * (int)gridDim.z;
    const int f = (int)blockIdx.z * nbx + (int)blockIdx.x;
    const int s = (f & 7) * (nf >> 3) + (f >> 3);
    const int bx = s % nbx;
    const int z = s / nbx;
    tm = (bx / nbn) * 256;
    tn = (bx % nbn) * 256;
    offA = (long)(z / nAi) * sAo + (long)(z % nAi) * sAi;
    offB = (long)(z / nBi) * sBo + (long)(z % nBi) * sBi;
    offC = (long)(z / nCi) * sCo + (long)(z % nCi) * sCi;
  } else {
    const int nwg = (int)gridDim.x;
    const int bid = (int)blockIdx.x;
    const int s = (bid & 7) * (nwg >> 3) + (bid >> 3);
    const int sTile = s >> 4, w = s & 15;
    const int snb = nbn >> 2;
    tm = ((sTile / snb) * 4 + (w >> 2)) * 256;
    tn = ((sTile % snb) * 4 + (w & 3)) * 256;
  }

  const int tid = (int)threadIdx.x;
  const int lane = tid & 63;
  const int wv = tid >> 6;      // 0..7
  const int wm = wv >> 2;       // 0..1 (A half)
  const int wn = wv & 3;        // 0..3
  const int l16 = lane & 15;
  const int kg = lane >> 4;

  // staging: linear LDS dest; content[o] = logical[o ^ ((row&7)<<4)], row=o>>7
  const int srow = tid >> 3;
  const int scolb = ((tid & 7) * 16) ^ (((tid >> 3) & 7) << 4);
  const unsigned short* Abase = A + offA + (long)tm * lda + (scolb >> 1);
  const unsigned short* Bbase = B + offB + (long)tn * ldb + (scolb >> 1);
  const int ldsw = wv * 1024;

  // frag read cols (full-XOR swizzle on byte col, row&7 == l16&7)
  const int colswz0 = (kg * 16) ^ ((l16 & 7) << 4);
  const int colswz1 = (64 + kg * 16) ^ ((l16 & 7) << 4);

  f32x4 acc[8][4];
  #pragma unroll
  for (int i = 0; i < 8; ++i)
    #pragma unroll
    for (int j = 0; j < 4; ++j)
      #pragma unroll
      for (int e = 0; e < 4; ++e) acc[i][j][e] = 0.f;

  auto stageAh = [&](int t, int h) {       // one A half-tile (2 loads)
    const int buf = t & 1;
    #pragma unroll
    for (int i = 0; i < 2; ++i)
      gl_lds16(Abase + (long)(h * 128 + srow + i * 64) * lda + t * 64,
               &LDS[buf * 32768 + h * 16384 + i * 8192 + ldsw]);
  };
  auto stageBh = [&](int t, int h) {       // one B half-tile (2 loads)
    const int buf = t & 1;
    #pragma unroll
    for (int i = 0; i < 2; ++i)
      gl_lds16(Bbase + (long)(h * 128 + srow + i * 64) * ldb + t * 64,
               &LDS[65536 + buf * 32768 + h * 16384 + i * 8192 + ldsw]);
  };

  // prologue: tiles 0,1 staged (8 loads each); wait tile 0 only
  stageAh(0, 0); stageAh(0, 1); stageBh(0, 0); stageBh(0, 1);
  stageAh(1, 0); stageAh(1, 1); stageBh(1, 0); stageBh(1, 1);
  asm volatile("s_waitcnt vmcnt(8)" ::: "memory");
  __builtin_amdgcn_s_barrier();

  for (int t = 0; t < NT; ++t) {
    const unsigned char* aB = &LDS[(t & 1) * 32768 + wm * 16384];
    const unsigned char* bB = &LDS[65536 + (t & 1) * 32768 + (wn >> 1) * 16384];
    const int brow = (wn & 1) * 64;
    bf16x8 bfrag[4][2];
    #pragma unroll
    for (int j = 0; j < 4; ++j) {
      bf16x8 a0k0 = *(const bf16x8*)(aB + ((2 * j + 0) * 16 + l16) * 128 + colswz0);
      bf16x8 a0k1 = *(const bf16x8*)(aB + ((2 * j + 0) * 16 + l16) * 128 + colswz1);
      bf16x8 a1k0 = *(const bf16x8*)(aB + ((2 * j + 1) * 16 + l16) * 128 + colswz0);
      bf16x8 a1k1 = *(const bf16x8*)(aB + ((2 * j + 1) * 16 + l16) * 128 + colswz1);
      if (j == 0) {
        #pragma unroll
        for (int ni = 0; ni < 4; ++ni) {
          bfrag[ni][0] = *(const bf16x8*)(bB + (brow + ni * 16 + l16) * 128 + colswz0);
          bfrag[ni][1] = *(const bf16x8*)(bB + (brow + ni * 16 + l16) * 128 + colswz1);
        }
        if (t > 0 && t + 1 < NT) stageAh(t + 1, 0);
      } else if (j == 1) {
        if (t > 0 && t + 1 < NT) stageAh(t + 1, 1);
      } else if (j == 2) {
        if (t + 2 < NT) stageBh(t + 2, 0);
      } else {
        if (t + 2 < NT) stageBh(t + 2, 1);
      }
      asm volatile("s_waitcnt lgkmcnt(0)" ::: "memory");
      __builtin_amdgcn_sched_barrier(0);
      if (j == 1) {
        __builtin_amdgcn_s_barrier();          // pre-MFMA: B(t)-slot protection
      } else if (j == 3) {
        if (t >= NT - 2) { asm volatile("s_waitcnt vmcnt(0)" ::: "memory"); }
        else             { asm volatile("s_waitcnt vmcnt(4)" ::: "memory"); }
        __builtin_amdgcn_sched_barrier(0);
        __builtin_amdgcn_s_barrier();          // pre-MFMA: tile boundary
      }
      __builtin_amdgcn_s_setprio(1);
      #pragma unroll
      for (int ni = 0; ni < 4; ++ni) {
        acc[2 * j + 0][ni] = __builtin_amdgcn_mfma_f32_16x16x32_bf16(a0k0, bfrag[ni][0], acc[2 * j + 0][ni], 0, 0, 0);
        acc[2 * j + 0][ni] = __builtin_amdgcn_mfma_f32_16x16x32_bf16(a0k1, bfrag[ni][1], acc[2 * j + 0][ni], 0, 0, 0);
        acc[2 * j + 1][ni] = __builtin_amdgcn_mfma_f32_16x16x32_bf16(a1k0, bfrag[ni][0], acc[2 * j + 1][ni], 0, 0, 0);
        acc[2 * j + 1][ni] = __builtin_amdgcn_mfma_f32_16x16x32_bf16(a1k1, bfrag[ni][1], acc[2 * j + 1][ni], 0, 0, 0);
      }
      __builtin_amdgcn_s_setprio(0);
    }
  }
  // Post-loop: every wave's ds_reads are drained (its own last lgkmcnt(0)),
  // and all waves passed the last tile's pre-MFMA barrier; remaining MFMA
  // work is register-only -> LDS safely reusable per-wave for the epilogue.

  // epilogue
  const int which = SPLIT3 ? (tn >> 12) : 0;
  const float* bp = SPLIT3 ? (which == 0 ? b0 : (which == 1 ? b1 : b2)) : b0;
  void* Cp = SPLIT3 ? (which == 0 ? C0 : (which == 1 ? C1 : C2)) : C0;
  const int tnn = SPLIT3 ? (tn & 4095) : tn;

  if (CF32) {
    // f32 path (final GEMM): nontemporal direct stores (never re-read)
    #pragma unroll
    for (int ni = 0; ni < 4; ++ni) {
      const int col = tnn + wn * 64 + ni * 16 + l16;
      const float bv = HAS_BIAS ? bp[col] : 0.f;
      #pragma unroll
      for (int mi = 0; mi < 8; ++mi)
        #pragma unroll
        for (int jj = 0; jj < 4; ++jj) {
          const int row = tm + wm * 128 + mi * 16 + kg * 4 + jj;
          __builtin_nontemporal_store(acc[mi][ni][jj] * alpha + bv,
                                      &((float*)Cp)[offC + (long)row * ldc + col]);
        }
    }
  } else if (SPLIT3 && which == 2) {
    // v group: write TRANSPOSED into vT (B*H, 512d, 512t).
    unsigned short* lw = (unsigned short*)&LDS[wv * 16384];
    #pragma unroll
    for (int ni = 0; ni < 4; ++ni) {
      const int dl = ni * 16 + l16;
      const float bv = HAS_BIAS ? bp[tnn + wn * 64 + dl] : 0.f;
      #pragma unroll
      for (int mi = 0; mi < 8; ++mi)
        #pragma unroll
        for (int jj = 0; jj < 4; ++jj) {
          const int tl = mi * 16 + kg * 4 + jj;
          lw[dl * 128 + (tl ^ ((dl & 7) << 4))] = f2bf(acc[mi][ni][jj] * alpha + bv);
        }
    }
    asm volatile("s_waitcnt lgkmcnt(0)" ::: "memory");
    __builtin_amdgcn_sched_barrier(0);
    const int b = tm >> 9, hh = tnn >> 9;
    const int dbase = (tnn & 511) + wn * 64;
    const int tbase = (tm & 511) + wm * 128;
    unsigned short* vTg = (unsigned short*)C2 +
                          ((long)(b * 8 + hh) * 512 + dbase) * 512 + tbase;
    const int dr = lane >> 4, t8 = (lane & 15) * 8;
    #pragma unroll
    for (int i = 0; i < 16; ++i) {
      const int dl = i * 4 + dr;
      short8 val = *(const short8*)&lw[dl * 128 + (t8 ^ ((dl & 7) << 4))];
      __builtin_nontemporal_store(val, (short8*)(vTg + (long)dl * 512 + t8));
    }
  } else {
    // bf16 path: per-wave LDS transpose -> fully coalesced 128B row segments
    unsigned short* lw = (unsigned short*)&LDS[wv * 16384];  // private 16KB
    #pragma unroll
    for (int ni = 0; ni < 4; ++ni) {
      const float bv = HAS_BIAS ? bp[tnn + wn * 64 + ni * 16 + l16] : 0.f;
      #pragma unroll
      for (int mi = 0; mi < 8; ++mi)
        #pragma unroll
        for (int jj = 0; jj < 4; ++jj)
          lw[(mi * 16 + kg * 4 + jj) * 64 + ni * 16 + l16] =
              f2bf(acc[mi][ni][jj] * alpha + bv);
    }
    asm volatile("s_waitcnt lgkmcnt(0)" ::: "memory");
    __builtin_amdgcn_sched_barrier(0);
    unsigned short* Cg = (unsigned short*)Cp + offC +
                         (long)(tm + wm * 128) * ldc + tnn + wn * 64;
    const int rr = lane >> 3, cc = (lane & 7) * 8;
    #pragma unroll
    for (int i = 0; i < 16; ++i) {
      short8 val = *(const short8*)&lw[(i * 8 + rr) * 64 + cc];
      *(short8*)(Cg + (long)(i * 8 + rr) * ldc + cc) = val;
    }
  }
}

// ============================================================================
// merged f32 -> bf16 convert over up to 4 consecutive dst ranges
// ============================================================================
__global__ __launch_bounds__(256)
void cvt_multi(const float* __restrict__ s0, long n0,
               const float* __restrict__ s1, long n1,
               const float* __restrict__ s2, long n2,
               const float* __restrict__ s3, long n3,
               unsigned short* __restrict__ dst, long n8)
{
  long i = (long)blockIdx.x * 256 + threadIdx.x;
  const long stride = (long)gridDim.x * 256;
  for (; i < n8; i += stride) {
    long e = i * 8;
    const float* src;
    if (e < n0)                    src = s0 + e;
    else if (e < n0 + n1)          src = s1 + (e - n0);
    else if (e < n0 + n1 + n2)     src = s2 + (e - n0 - n1);
    else                           src = s3 + (e - n0 - n1 - n2);
    f32x4 v0 = *(const f32x4*)(src);
    f32x4 v1 = *(const f32x4*)(src + 4);
    uint4v o;
    o[0] = cvt_pk_bf16(v0[0], v0[1]);
    o[1] = cvt_pk_bf16(v0[2], v0[3]);
    o[2] = cvt_pk_bf16(v1[0], v1[1]);
    o[3] = cvt_pk_bf16(v1[2], v1[3]);
    *(uint4v*)(dst + e) = o;
  }
}

// In-place LayerNorm over rows of 512 bf16 for q then k (merged). One wave/row.
__global__ __launch_bounds__(256)
void ln_rows2(unsigned short* __restrict__ q, const float* __restrict__ gq,
              const float* __restrict__ bq_, unsigned short* __restrict__ k,
              const float* __restrict__ gk, const float* __restrict__ bk_,
              int rows_per_tensor)
{
  int row = blockIdx.x * 4 + ((int)threadIdx.x >> 6);
  const int lane = (int)threadIdx.x & 63;
  unsigned short* base = q;
  const float* g = gq;
  const float* b = bq_;
  if (row >= rows_per_tensor) { row -= rows_per_tensor; base = k; g = gk; b = bk_; }
  unsigned short* p = base + (long)row * 512 + lane * 8;
  short8 rv = *(const short8*)p;
  float x[8];
  #pragma unroll
  for (int j = 0; j < 8; ++j) x[j] = bf2f((unsigned short)rv[j]);
  float s = 0.f;
  #pragma unroll
  for (int j = 0; j < 8; ++j) s += x[j];
  #pragma unroll
  for (int off = 32; off > 0; off >>= 1) s += __shfl_xor(s, off, 64);
  float mu = s * (1.f / 512.f);
  float vs = 0.f;
  #pragma unroll
  for (int j = 0; j < 8; ++j) { float d = x[j] - mu; vs += d * d; }
  #pragma unroll
  for (int off = 32; off > 0; off >>= 1) vs += __shfl_xor(vs, off, 64);
  float rs = rsqrtf(vs * (1.f / 512.f) + 1e-5f);
  f32x4 gv0 = *(const f32x4*)(g + lane * 8);
  f32x4 gv1 = *(const f32x4*)(g + lane * 8 + 4);
  f32x4 bv0 = *(const f32x4*)(b + lane * 8);
  f32x4 bv1 = *(const f32x4*)(b + lane * 8 + 4);
  short8 ov;
  #pragma unroll
  for (int j = 0; j < 4; ++j) ov[j] = (short)f2bf((x[j] - mu) * rs * gv0[j] + bv0[j]);
  #pragma unroll
  for (int j = 0; j < 4; ++j) ov[4 + j] = (short)f2bf((x[4 + j] - mu) * rs * gv1[j] + bv1[j]);
  *(short8*)p = ov;
}

// w = (val * gelu_exact(gate)) / max(||.||2, 1e-12); h rows are 1024 (val|gate)
__global__ __launch_bounds__(256)
void gate_norm(const unsigned short* __restrict__ h, unsigned short* __restrict__ w)
{
  const int row = blockIdx.x * 4 + ((int)threadIdx.x >> 6);
  const int lane = (int)threadIdx.x & 63;
  const unsigned short* hp = h + (long)row * 1024 + lane * 8;
  short8 vv = *(const short8*)hp;
  short8 gg = *(const short8*)(hp + 512);
  float wv[8];
  float ssq = 0.f;
  #pragma unroll
  for (int j = 0; j < 8; ++j) {
    float val = bf2f((unsigned short)vv[j]);
    float gt  = bf2f((unsigned short)gg[j]);
    float tt  = val * (0.5f * gt * (1.f + erff(gt * 0.70710678118654752f)));
    wv[j] = tt;
    ssq += tt * tt;
  }
  #pragma unroll
  for (int off = 32; off > 0; off >>= 1) ssq += __shfl_xor(ssq, off, 64);
  float scale = 1.f / fmaxf(sqrtf(ssq), 1e-12f);
  short8 ov;
  #pragma unroll
  for (int j = 0; j < 8; ++j) ov[j] = (short)f2bf(wv[j] * scale);
  *(short8*)(w + (long)row * 512 + lane * 8) = ov;
}

extern "C" void kernel_launch(void* const* d_in, const int* in_sizes, int n_in,
                              void* d_out, int out_size, void* d_ws, size_t ws_size,
                              hipStream_t stream)
{
  (void)in_sizes; (void)n_in; (void)out_size; (void)ws_size;
  const float* x   = (const float*)d_in[0];
  const float* Wq  = (const float*)d_in[1];
  const float* bq  = (const float*)d_in[2];
  const float* Wk  = (const float*)d_in[3];
  const float* bk  = (const float*)d_in[4];
  const float* Wv  = (const float*)d_in[5];
  const float* bv  = (const float*)d_in[6];
  const float* g_q = (const float*)d_in[7];
  const float* b_q = (const float*)d_in[8];
  const float* g_k = (const float*)d_in[9];
  const float* b_k = (const float*)d_in[10];
  const float* Wg  = (const float*)d_in[11];
  const float* bg  = (const float*)d_in[12];
  const float* Wo  = (const float*)d_in[13];
  const float* bo  = (const float*)d_in[14];
  float* out = (float*)d_out;

  const long NE  = 33554432L;   // B*S*E
  const long NE2 = NE / 2;      // 4096*4096
  unsigned short* ws    = (unsigned short*)d_ws;
  unsigned short* xb    = ws;                    // [0, NE)
  unsigned short* Wqkv  = ws + NE;               // [NE, 2.5NE) Wq|Wk|Wv
  unsigned short* qbuf  = ws + NE + 3 * NE2;     // [2.5NE, 3.5NE)
  unsigned short* kbuf  = qbuf + NE;             // [3.5NE, 4.5NE)
  unsigned short* vT    = kbuf + NE;             // [4.5NE, 5.5NE) (B*H,512d,512t)
  unsigned short* Wgb   = Wqkv;                  // 1024x512 (after proj)
  unsigned short* Wob   = Wqkv + 524288;         // 4096x4096 (after proj)
  unsigned short* sbuf  = xb;                    // scores (x dead after proj)
  unsigned short* hbuf  = qbuf;                  // spans qbuf+kbuf (dead after scores)
  unsigned short* wbuf  = xb;                    // scores dead after h-GEMM
  unsigned short* obuf  = kbuf;                  // h dead after gate_norm

  dim3 blk256(256), blk512(512);
  const float isq = 0.044194173824159216f;  // 1/sqrt(512)

  // one merged convert: x | Wq | Wk | Wv  ->  ws[0 .. 2.5NE)
  cvt_multi<<<20480, blk256, 0, stream>>>(x, NE, Wq, NE2, Wk, NE2, Wv, NE2,
                                          ws, (NE + 3 * NE2) / 8);

  // merged q|k|v projection: split-3 epilogue; v written transposed into vT
  gemm256<0, 1, 0, 1><<<1536, blk512, 0, stream>>>(
      xb, Wqkv, bq, bk, bv, qbuf, kbuf, vT,
      4096, 4096, 4096, 4096, 48, 1.f,
      0L, 0L, 1, 0L, 0L, 1, 0L, 0L, 1);

  // Wqkv dead -> convert Wg, Wo into its region (one launch)
  cvt_multi<<<8192, blk256, 0, stream>>>(Wg, 524288L, Wo, NE2,
                                         nullptr, 0L, nullptr, 0L,
                                         Wgb, (524288L + NE2) / 8);

  // layernorm q and k (merged)
  ln_rows2<<<32768, blk256, 0, stream>>>(qbuf, g_q, b_q, kbuf, g_k, b_k, 65536);

  // scores = q @ k^T / sqrt(HD), per (b,h) -> sbuf (=xb)
  gemm256<1, 0, 0, 0><<<dim3(4, 1, 128), blk512, 0, stream>>>(
      qbuf, kbuf, nullptr, nullptr, nullptr, sbuf, nullptr, nullptr,
      512, 4096, 4096, 512, 2, isq,
      2097152L, 512L, 8,
      2097152L, 512L, 8,
      262144L, 0L, 1);

  // h = scores @ Wg^T + bg -> hbuf (=qbuf..kbuf)
  gemm256<1, 0, 0, 1><<<dim3(8, 1, 128), blk512, 0, stream>>>(
      sbuf, Wgb, bg, nullptr, nullptr, hbuf, nullptr, nullptr,
      512, 512, 512, 1024, 4, 1.f,
      262144L, 0L, 1,
      0L, 0L, 1,
      524288L, 0L, 1);

  gate_norm<<<16384, blk256, 0, stream>>>(hbuf, wbuf);

  // attn_out = w @ vT^T -> obuf (=kbuf), (B,S,E) layout
  gemm256<1, 0, 0, 0><<<dim3(4, 1, 128), blk512, 0, stream>>>(
      wbuf, vT, nullptr, nullptr, nullptr, obuf, nullptr, nullptr,
      512, 512, 512, 4096, 2, 1.f,
      262144L, 0L, 1,
      262144L, 0L, 1,
      2097152L, 512L, 8);

  // final = attn_out @ Wo^T + bo -> d_out (f32, nontemporal)
  gemm256<0, 0, 1, 1><<<512, blk512, 0, stream>>>(
      obuf, Wob, bo, nullptr, nullptr, out, nullptr, nullptr,
      4096, 4096, 4096, 4096, 16, 1.f,
      0L, 0L, 1, 0L, 0L, 1, 0L, 0L, 1);
}